// Round 1
// baseline (485.320 us; speedup 1.0000x reference)
//
#include <hip/hip_runtime.h>
#include <hip/hip_bf16.h>

#define NN    8192
#define DINC  256
#define HIDC  512

__device__ __forceinline__ float lrelu02(float v) { return v > 0.0f ? v : 0.2f * v; }

// ---------------------------------------------------------------------------
// Tiled fp32 GEMM: C[m, col_off + n] = act(sum_k A[m,k] * B[k,n] + bias[n])
// A: M x K (lda = K), B: K x Nc, C: ldc stride. Block tile 64x64, BK=16.
// ---------------------------------------------------------------------------
__global__ __launch_bounds__(256) void gemm_f32(
    const float* __restrict__ A, const float* __restrict__ B,
    const float* __restrict__ bias, float* __restrict__ C,
    int K, int Nc, int ldc, int col_off, int relu_flag)
{
    __shared__ float As[16][64];
    __shared__ float Bs[16][68];
    const int t  = threadIdx.x;
    const int bx = blockIdx.x, by = blockIdx.y;
    const int tx = t & 15, ty = t >> 4;
    const int arow = t >> 2,  acol = (t & 3) << 2;   // A tile: 64 rows x 16 cols
    const int brow = t >> 4,  bcol = (t & 15) << 2;  // B tile: 16 rows x 64 cols

    const float* Ab = A + (size_t)(by * 64 + arow) * K + acol;
    const float* Bb = B + (size_t)brow * Nc + bx * 64 + bcol;

    float acc[4][4];
#pragma unroll
    for (int i = 0; i < 4; ++i)
#pragma unroll
        for (int j = 0; j < 4; ++j) acc[i][j] = 0.0f;

    for (int k0 = 0; k0 < K; k0 += 16) {
        float4 av = *(const float4*)(Ab + k0);
        float4 bv = *(const float4*)(Bb + (size_t)k0 * Nc);
        __syncthreads();
        As[acol + 0][arow] = av.x;
        As[acol + 1][arow] = av.y;
        As[acol + 2][arow] = av.z;
        As[acol + 3][arow] = av.w;
        *(float4*)&Bs[brow][bcol] = bv;
        __syncthreads();
#pragma unroll
        for (int kk = 0; kk < 16; ++kk) {
            float4 a4 = *(const float4*)&As[kk][ty << 2];
            float4 b4 = *(const float4*)&Bs[kk][tx << 2];
            float a[4] = {a4.x, a4.y, a4.z, a4.w};
            float b[4] = {b4.x, b4.y, b4.z, b4.w};
#pragma unroll
            for (int i = 0; i < 4; ++i)
#pragma unroll
                for (int j = 0; j < 4; ++j)
                    acc[i][j] = fmaf(a[i], b[j], acc[i][j]);
        }
    }
    const int gm = by * 64 + (ty << 2);
    const int gn = bx * 64 + (tx << 2);
#pragma unroll
    for (int i = 0; i < 4; ++i) {
#pragma unroll
        for (int j = 0; j < 4; ++j) {
            float v = acc[i][j] + (bias ? bias[gn + j] : 0.0f);
            if (relu_flag) v = fmaxf(v, 0.0f);
            C[(size_t)(gm + i) * ldc + col_off + gn + j] = v;
        }
    }
}

// ---------------------------------------------------------------------------
// Histogram + dedupe. GAT: count incoming edges per dst (self-loops implicit).
// GIN: dedupe (src,dst) pairs via N*N bitmap; owner edges counted per src.
// ---------------------------------------------------------------------------
__global__ __launch_bounds__(256) void build_hist(
    const int* __restrict__ src, const int* __restrict__ dst, int E, int N,
    int* __restrict__ cnt_dst, int* __restrict__ cnt_src,
    unsigned int* __restrict__ bitmap, unsigned char* __restrict__ flags)
{
    int e = blockIdx.x * 256 + threadIdx.x;
    if (e >= E) return;
    int s = src[e], d = dst[e];
    atomicAdd(&cnt_dst[d], 1);
    unsigned int key  = (unsigned int)s * (unsigned int)N + (unsigned int)d;
    unsigned int word = key >> 5;
    unsigned int bit  = 1u << (key & 31u);
    unsigned int old  = atomicOr(&bitmap[word], bit);
    int own = (old & bit) == 0u;
    flags[e] = (unsigned char)own;
    if (own) atomicAdd(&cnt_src[s], 1);
}

// Exclusive scan of 8192 counts -> off[0..N], cur copy for scatter cursors.
__global__ __launch_bounds__(1024) void scan8192(
    const int* __restrict__ cnt, int* __restrict__ off, int* __restrict__ cur)
{
    __shared__ int lds[1024];
    const int t = threadIdx.x;
    const int base = t * 8;
    int v[8]; int s = 0;
#pragma unroll
    for (int j = 0; j < 8; ++j) { v[j] = cnt[base + j]; s += v[j]; }
    lds[t] = s;
    __syncthreads();
    int mine = s;
    for (int o = 1; o < 1024; o <<= 1) {
        int add = (t >= o) ? lds[t - o] : 0;
        __syncthreads();
        lds[t] += add;
        __syncthreads();
    }
    int run = lds[t] - mine;  // exclusive prefix of this thread's chunk
#pragma unroll
    for (int j = 0; j < 8; ++j) { off[base + j] = run; cur[base + j] = run; run += v[j]; }
    if (t == 1023) off[8192] = run;
}

__global__ __launch_bounds__(256) void scatter_edges(
    const int* __restrict__ src, const int* __restrict__ dst, int E,
    int* __restrict__ cur_dst, int* __restrict__ cur_src,
    const unsigned char* __restrict__ flags,
    int* __restrict__ csr_eid, int* __restrict__ csr_gin)
{
    int e = blockIdx.x * 256 + threadIdx.x;
    if (e >= E) return;
    int d = dst[e];
    int p = atomicAdd(&cur_dst[d], 1);
    csr_eid[p] = e;
    if (flags[e]) {
        int s = src[e];
        int q = atomicAdd(&cur_src[s], 1);
        csr_gin[q] = d;
    }
}

// ---------------------------------------------------------------------------
// Per-edge GATv2 scores: e[edge][h] = sum_k lrelu(xl[s,h,k]+xr[d,h,k])*att[h,k]
// One 64-lane wave per edge; lane loads float4 of the 256-wide row.
// Edges [E, E+N) are the implicit self-loops (s = d = e - E).
// ---------------------------------------------------------------------------
__global__ __launch_bounds__(256) void edge_scores(
    const float* __restrict__ xl, const float* __restrict__ xr,
    const float* __restrict__ att,
    const int* __restrict__ src, const int* __restrict__ dst,
    int E_total, int E_real, float* __restrict__ evals)
{
    int e = blockIdx.x * 4 + (threadIdx.x >> 6);
    if (e >= E_total) return;
    int lane = threadIdx.x & 63;
    int s, d;
    if (e < E_real) { s = src[e]; d = dst[e]; }
    else            { s = e - E_real; d = s; }
    float4 a = *(const float4*)&xl[(size_t)s * DINC + lane * 4];
    float4 b = *(const float4*)&xr[(size_t)d * DINC + lane * 4];
    float4 w = *(const float4*)&att[lane * 4];
    float p = lrelu02(a.x + b.x) * w.x + lrelu02(a.y + b.y) * w.y +
              lrelu02(a.z + b.z) * w.z + lrelu02(a.w + b.w) * w.w;
    p += __shfl_xor(p, 1);
    p += __shfl_xor(p, 2);
    p += __shfl_xor(p, 4);
    p += __shfl_xor(p, 8);
    if ((lane & 15) == 0) evals[(size_t)e * 4 + (lane >> 4)] = p;
}

// ---------------------------------------------------------------------------
// GAT per-node softmax + weighted aggregation. Block (256 thr) per node.
// Thread k handles output feature k (head h = k>>6). Writes cat[:, 0:256].
// ---------------------------------------------------------------------------
__global__ __launch_bounds__(256) void gat_aggregate(
    const float* __restrict__ xl, const float* __restrict__ evals,
    const int* __restrict__ csr_eid, const int* __restrict__ off_dst,
    const int* __restrict__ src, const float* __restrict__ b_gat,
    float* __restrict__ cat, int E_real)
{
    const int d = blockIdx.x;
    const int k = threadIdx.x;
    const int h = k >> 6;
    const int beg = off_dst[d], end = off_dst[d + 1];

    float e_self = evals[(size_t)(E_real + d) * 4 + h];
    float m = e_self;
    for (int j = beg; j < end; ++j) {
        int ei = csr_eid[j];
        m = fmaxf(m, evals[(size_t)ei * 4 + h]);
    }
    float wself = __expf(e_self - m);
    float denom = wself;
    float acc = wself * xl[(size_t)d * DINC + k];
    for (int j = beg; j < end; ++j) {
        int ei = csr_eid[j];
        float w = __expf(evals[(size_t)ei * 4 + h] - m);
        denom += w;
        int s = src[ei];
        acc += w * xl[(size_t)s * DINC + k];
    }
    cat[(size_t)d * HIDC + k] = acc / denom + b_gat[k];
}

// GIN aggregation: h[i] = x[i] + sum_{deduped edges (i->j)} x[j]
__global__ __launch_bounds__(256) void gin_aggregate(
    const float* __restrict__ x, const int* __restrict__ csr_gin,
    const int* __restrict__ off_src, float* __restrict__ hbuf)
{
    const int i = blockIdx.x;
    const int k = threadIdx.x;
    const int beg = off_src[i], end = off_src[i + 1];
    float acc = x[(size_t)i * DINC + k];
    for (int j = beg; j < end; ++j)
        acc += x[(size_t)csr_gin[j] * DINC + k];
    hbuf[(size_t)i * DINC + k] = acc;
}

// LayerNorm over 512 features; block per row, thread handles 2 features.
__global__ __launch_bounds__(256) void layernorm512(
    const float* __restrict__ cbuf, const float* __restrict__ g,
    const float* __restrict__ b, float* __restrict__ out)
{
    const int r = blockIdx.x;
    const int t = threadIdx.x;
    float2 v = *(const float2*)&cbuf[(size_t)r * HIDC + t * 2];
    float s = v.x + v.y;
    float q = v.x * v.x + v.y * v.y;
    for (int o = 1; o < 64; o <<= 1) {
        s += __shfl_xor(s, o);
        q += __shfl_xor(q, o);
    }
    __shared__ float ls[4], lq[4];
    int w = t >> 6;
    if ((t & 63) == 0) { ls[w] = s; lq[w] = q; }
    __syncthreads();
    s = ls[0] + ls[1] + ls[2] + ls[3];
    q = lq[0] + lq[1] + lq[2] + lq[3];
    float mu  = s * (1.0f / 512.0f);
    float var = q * (1.0f / 512.0f) - mu * mu;
    float rs  = rsqrtf(var + 1e-5f);
    int c0 = t * 2;
    out[(size_t)r * HIDC + c0]     = (v.x - mu) * rs * g[c0]     + b[c0];
    out[(size_t)r * HIDC + c0 + 1] = (v.y - mu) * rs * g[c0 + 1] + b[c0 + 1];
}

// ---------------------------------------------------------------------------
extern "C" void kernel_launch(void* const* d_in, const int* in_sizes, int n_in,
                              void* d_out, int out_size, void* d_ws, size_t ws_size,
                              hipStream_t stream)
{
    const float* x      = (const float*)d_in[0];
    const float* W_l    = (const float*)d_in[1];
    const float* W_r    = (const float*)d_in[2];
    const float* att    = (const float*)d_in[3];
    const float* b_gat  = (const float*)d_in[4];
    const float* gin_W1 = (const float*)d_in[5];
    const float* gin_b1 = (const float*)d_in[6];
    const float* gin_W2 = (const float*)d_in[7];
    const float* gin_b2 = (const float*)d_in[8];
    const float* fus_W  = (const float*)d_in[9];
    const float* fus_b  = (const float*)d_in[10];
    const float* ln_g   = (const float*)d_in[11];
    const float* ln_b   = (const float*)d_in[12];
    const int*   eidx   = (const int*)d_in[13];

    const int E  = in_sizes[13] / 2;
    const int N  = in_sizes[0] / DINC;   // 8192
    const int ET = E + N;
    const int* src = eidx;
    const int* dst = eidx + E;

    char* ws = (char*)d_ws;
    size_t off = 0;
    auto alloc = [&](size_t bytes) -> void* {
        void* p = ws + off;
        off = (off + bytes + 255) & ~(size_t)255;
        return p;
    };
    float* xl    = (float*)alloc((size_t)N * DINC * 4);
    float* xr    = (float*)alloc((size_t)N * DINC * 4);
    float* evals = (float*)alloc((size_t)ET * 4 * 4);
    float* cat   = (float*)alloc((size_t)N * HIDC * 4);
    float* hbuf  = (float*)alloc((size_t)N * DINC * 4);
    float* gin1  = (float*)alloc((size_t)N * DINC * 4);
    float* cbuf  = (float*)alloc((size_t)N * HIDC * 4);
    int* cnt_dst = (int*)alloc((size_t)N * 4);
    int* off_dst = (int*)alloc((size_t)(N + 1) * 4);
    int* cur_dst = (int*)alloc((size_t)N * 4);
    int* cnt_src = (int*)alloc((size_t)N * 4);
    int* off_src = (int*)alloc((size_t)(N + 1) * 4);
    int* cur_src = (int*)alloc((size_t)N * 4);
    int* csr_eid = (int*)alloc((size_t)E * 4);
    int* csr_gin = (int*)alloc((size_t)E * 4);
    unsigned char* flags  = (unsigned char*)alloc((size_t)E);
    unsigned int*  bitmap = (unsigned int*)alloc((size_t)N * (size_t)N / 8);

    hipMemsetAsync(cnt_dst, 0, (size_t)N * 4, stream);
    hipMemsetAsync(cnt_src, 0, (size_t)N * 4, stream);
    hipMemsetAsync(bitmap, 0, (size_t)N * (size_t)N / 8, stream);

    // xl = x @ W_l, xr = x @ W_r
    dim3 gA(DINC / 64, N / 64);
    gemm_f32<<<gA, 256, 0, stream>>>(x, W_l, nullptr, xl, DINC, DINC, DINC, 0, 0);
    gemm_f32<<<gA, 256, 0, stream>>>(x, W_r, nullptr, xr, DINC, DINC, DINC, 0, 0);

    // CSR build (both directions) + dedupe for GIN
    build_hist<<<(E + 255) / 256, 256, 0, stream>>>(src, dst, E, N, cnt_dst, cnt_src, bitmap, flags);
    scan8192<<<1, 1024, 0, stream>>>(cnt_dst, off_dst, cur_dst);
    scan8192<<<1, 1024, 0, stream>>>(cnt_src, off_src, cur_src);
    scatter_edges<<<(E + 255) / 256, 256, 0, stream>>>(src, dst, E, cur_dst, cur_src, flags, csr_eid, csr_gin);

    // per-edge GATv2 scores (incl. self-loops)
    edge_scores<<<(ET + 3) / 4, 256, 0, stream>>>(xl, xr, att, src, dst, ET, E, evals);

    // node aggregations
    gat_aggregate<<<N, 256, 0, stream>>>(xl, evals, csr_eid, off_dst, src, b_gat, cat, E);
    gin_aggregate<<<N, 256, 0, stream>>>(x, csr_gin, off_src, hbuf);

    // GIN MLP
    gemm_f32<<<gA, 256, 0, stream>>>(hbuf, gin_W1, gin_b1, gin1, DINC, DINC, DINC, 0, 1);
    gemm_f32<<<gA, 256, 0, stream>>>(gin1, gin_W2, gin_b2, cat, DINC, DINC, HIDC, DINC, 0);

    // fusion: relu(cat @ fus_W + fus_b), then LayerNorm
    dim3 gF(HIDC / 64, N / 64);
    gemm_f32<<<gF, 256, 0, stream>>>(cat, fus_W, fus_b, cbuf, HIDC, HIDC, HIDC, 0, 1);
    layernorm512<<<N, 256, 0, stream>>>(cbuf, ln_g, ln_b, (float*)d_out);

    (void)n_in; (void)out_size; (void)ws_size;
}

// Round 2
// 278.722 us; speedup vs baseline: 1.7412x; 1.7412x over previous
//
#include <hip/hip_runtime.h>

typedef __bf16 bf16;
typedef __attribute__((ext_vector_type(8))) __bf16 bf16x8;
typedef __attribute__((ext_vector_type(4))) float f32x4;

#define DINC 256
#define HIDC 512

__device__ __forceinline__ float lrelu02(float v) { return v > 0.0f ? v : 0.2f * v; }

__device__ __forceinline__ void gload_lds16(const void* g, void* l) {
    __builtin_amdgcn_global_load_lds(
        (const __attribute__((address_space(1))) unsigned int*)g,
        (__attribute__((address_space(3))) unsigned int*)l, 16, 0, 0);
}

// ---------------------------------------------------------------------------
// bf16 MFMA GEMM, 128x128 tile, BK=32, m97 2-barrier structure.
// A: [M][K] bf16 row-major. Bt: [N][K] bf16 (pre-transposed weights).
// C[row][col_off + col] = act(A@B + bias). 256 thr = 4 waves, wave = 64x64.
// ---------------------------------------------------------------------------
template<int RELU, int OUTBF16>
__global__ __launch_bounds__(256) void gemm_mfma(
    const bf16* __restrict__ A, const bf16* __restrict__ Bt,
    const float* __restrict__ bias, void* __restrict__ Cout,
    int K, int ldc, int col_off)
{
    __shared__ bf16 As[128 * 32];
    __shared__ bf16 Bs[128 * 32];
    const int t = threadIdx.x;
    const int w = t >> 6, lane = t & 63;
    const long brow = (long)blockIdx.y * 128;
    const long bcol = (long)blockIdx.x * 128;
    const int wr = (w >> 1) * 64, wc = (w & 1) * 64;
    const int fr = lane & 15, half = lane >> 4;
    const int srow = lane >> 2;          // staging: row within 16-row chunk
    const int skof = (lane & 3) * 8;     // staging: k offset (elements)

    f32x4 acc[4][4] = {};

    for (int k0 = 0; k0 < K; k0 += 32) {
        __syncthreads();
#pragma unroll
        for (int c2 = 0; c2 < 2; ++c2) {
            const int c = w + c2 * 4;            // chunk 0..7 (16 rows each)
            const int row = c * 16 + srow;
            gload_lds16(A  + (brow + row) * K + k0 + skof, &As[c * 512]);
            gload_lds16(Bt + (bcol + row) * K + k0 + skof, &Bs[c * 512]);
        }
        __syncthreads();
        bf16x8 af[4], bfr[4];
#pragma unroll
        for (int i = 0; i < 4; ++i)
            af[i] = *(const bf16x8*)&As[(wr + i * 16 + fr) * 32 + half * 8];
#pragma unroll
        for (int j = 0; j < 4; ++j)
            bfr[j] = *(const bf16x8*)&Bs[(wc + j * 16 + fr) * 32 + half * 8];
#pragma unroll
        for (int i = 0; i < 4; ++i)
#pragma unroll
            for (int j = 0; j < 4; ++j)
                acc[i][j] = __builtin_amdgcn_mfma_f32_16x16x32_bf16(
                    af[i], bfr[j], acc[i][j], 0, 0, 0);
    }

#pragma unroll
    for (int i = 0; i < 4; ++i) {
#pragma unroll
        for (int j = 0; j < 4; ++j) {
            const long gcol = bcol + wc + j * 16 + fr;
            const float bv = bias ? bias[gcol] : 0.0f;
#pragma unroll
            for (int v = 0; v < 4; ++v) {
                const long grow = brow + wr + i * 16 + half * 4 + v;
                float val = acc[i][j][v] + bv;
                if (RELU) val = fmaxf(val, 0.0f);
                if (OUTBF16) ((bf16*)Cout)[grow * ldc + col_off + gcol] = (bf16)val;
                else         ((float*)Cout)[grow * ldc + col_off + gcol] = val;
            }
        }
    }
}

// ---------------------------------------------------------------------------
// prep: jobs 0-4 transpose+convert weights to bf16 [N][K]; job 5 converts x.
// ---------------------------------------------------------------------------
__global__ __launch_bounds__(256) void prep(
    const float* __restrict__ W_l, const float* __restrict__ W_r,
    const float* __restrict__ gin_W1, const float* __restrict__ gin_W2,
    const float* __restrict__ fus_W, const float* __restrict__ x,
    bf16* __restrict__ Wlr_t, bf16* __restrict__ W1t, bf16* __restrict__ W2t,
    bf16* __restrict__ Wft, bf16* __restrict__ xb)
{
    const int job = blockIdx.y;
    const int idx = blockIdx.x * 256 + threadIdx.x;
    if (job == 5) {
        // x: 8192*256 floats, 8 per thread
        const float4* xv = (const float4*)x;
        float4 a = xv[(size_t)idx * 2], b = xv[(size_t)idx * 2 + 1];
        bf16x8 o;
        o[0] = (bf16)a.x; o[1] = (bf16)a.y; o[2] = (bf16)a.z; o[3] = (bf16)a.w;
        o[4] = (bf16)b.x; o[5] = (bf16)b.y; o[6] = (bf16)b.z; o[7] = (bf16)b.w;
        *(bf16x8*)&xb[(size_t)idx * 8] = o;
        return;
    }
    const float* src; bf16* dst; int K, Nc;
    switch (job) {
        case 0: src = W_l;    dst = Wlr_t;             K = 256; Nc = 256; break;
        case 1: src = W_r;    dst = Wlr_t + 256 * 256; K = 256; Nc = 256; break;
        case 2: src = gin_W1; dst = W1t;               K = 256; Nc = 256; break;
        case 3: src = gin_W2; dst = W2t;               K = 256; Nc = 256; break;
        default: src = fus_W; dst = Wft;               K = 512; Nc = 512; break;
    }
    if (idx >= K * Nc) return;
    const int n = idx / K, k = idx % K;
    dst[idx] = (bf16)src[(size_t)k * Nc + n];
}

// ---------------------------------------------------------------------------
// CSR build (unchanged structure from round 1, csr stores node ids directly)
// ---------------------------------------------------------------------------
__global__ __launch_bounds__(256) void build_hist(
    const int* __restrict__ src, const int* __restrict__ dst, int E, int N,
    int* __restrict__ cnt_dst, int* __restrict__ cnt_src,
    unsigned int* __restrict__ bitmap, unsigned char* __restrict__ flags)
{
    int e = blockIdx.x * 256 + threadIdx.x;
    if (e >= E) return;
    int s = src[e], d = dst[e];
    atomicAdd(&cnt_dst[d], 1);
    unsigned int key  = (unsigned int)s * (unsigned int)N + (unsigned int)d;
    unsigned int word = key >> 5;
    unsigned int bit  = 1u << (key & 31u);
    unsigned int old  = atomicOr(&bitmap[word], bit);
    int own = (old & bit) == 0u;
    flags[e] = (unsigned char)own;
    if (own) atomicAdd(&cnt_src[s], 1);
}

__global__ __launch_bounds__(1024) void scan_both(
    const int* __restrict__ cnt_dst, int* __restrict__ off_dst, int* __restrict__ cur_dst,
    const int* __restrict__ cnt_src, int* __restrict__ off_src, int* __restrict__ cur_src)
{
    const int* cnt = blockIdx.x ? cnt_src : cnt_dst;
    int* off = blockIdx.x ? off_src : off_dst;
    int* cur = blockIdx.x ? cur_src : cur_dst;
    __shared__ int lds[1024];
    const int t = threadIdx.x;
    const int base = t * 8;
    int v[8]; int s = 0;
#pragma unroll
    for (int j = 0; j < 8; ++j) { v[j] = cnt[base + j]; s += v[j]; }
    lds[t] = s;
    __syncthreads();
    int mine = s;
    for (int o = 1; o < 1024; o <<= 1) {
        int add = (t >= o) ? lds[t - o] : 0;
        __syncthreads();
        lds[t] += add;
        __syncthreads();
    }
    int run = lds[t] - mine;
#pragma unroll
    for (int j = 0; j < 8; ++j) { off[base + j] = run; cur[base + j] = run; run += v[j]; }
    if (t == 1023) off[8192] = run;
}

__global__ __launch_bounds__(256) void scatter_edges(
    const int* __restrict__ src, const int* __restrict__ dst, int E,
    int* __restrict__ cur_dst, int* __restrict__ cur_src,
    const unsigned char* __restrict__ flags,
    int* __restrict__ csr_src, int* __restrict__ csr_gin)
{
    int e = blockIdx.x * 256 + threadIdx.x;
    if (e >= E) return;
    int s = src[e], d = dst[e];
    int p = atomicAdd(&cur_dst[d], 1);
    csr_src[p] = s;
    if (flags[e]) {
        int q = atomicAdd(&cur_src[s], 1);
        csr_gin[q] = d;
    }
}

// ---------------------------------------------------------------------------
// Fused GATv2: block per dst node, single pass, online softmax.
// xlr: [N][512] bf16 (cols 0-255 = xl, 256-511 = xr). Writes cat[:,0:256].
// Thread t = feature t, wave = head (64 feats/head). Scores wave-uniform.
// ---------------------------------------------------------------------------
__global__ __launch_bounds__(256) void gat_fused(
    const bf16* __restrict__ xlr, const int* __restrict__ csr_src,
    const int* __restrict__ off_dst, const float* __restrict__ att,
    const float* __restrict__ b_gat, bf16* __restrict__ cat)
{
    const int d = blockIdx.x, t = threadIdx.x;
    const int beg = off_dst[d], end = off_dst[d + 1];
    const float attv = att[t];
    const float xrv = (float)xlr[(size_t)d * HIDC + 256 + t];
    const float xld = (float)xlr[(size_t)d * HIDC + t];

    // self-loop score
    float p = lrelu02(xld + xrv) * attv;
#pragma unroll
    for (int o = 1; o < 64; o <<= 1) p += __shfl_xor(p, o);
    float m = p;            // running max (wave-uniform per head)
    float denom = 1.0f;     // exp(e_self - m) = 1
    float acc = xld;

    for (int j = beg; j < end; ++j) {
        const int s = csr_src[j];
        const float xls = (float)xlr[(size_t)s * HIDC + t];
        float q = lrelu02(xls + xrv) * attv;
#pragma unroll
        for (int o = 1; o < 64; o <<= 1) q += __shfl_xor(q, o);
        if (q > m) {                       // wave-uniform branch
            const float r = __expf(m - q);
            denom = denom * r + 1.0f;
            acc   = acc * r + xls;
            m = q;
        } else {
            const float wgt = __expf(q - m);
            denom += wgt;
            acc   += wgt * xls;
        }
    }
    cat[(size_t)d * HIDC + t] = (bf16)(acc / denom + b_gat[t]);
}

// GIN aggregation: h[i] = x[i] + sum over deduped out-edges x[dst], bf16 in/out
__global__ __launch_bounds__(256) void gin_aggregate(
    const bf16* __restrict__ xb, const int* __restrict__ csr_gin,
    const int* __restrict__ off_src, bf16* __restrict__ hbuf)
{
    const int i = blockIdx.x, t = threadIdx.x;
    const int beg = off_src[i], end = off_src[i + 1];
    float acc = (float)xb[(size_t)i * DINC + t];
    for (int j = beg; j < end; ++j)
        acc += (float)xb[(size_t)csr_gin[j] * DINC + t];
    hbuf[(size_t)i * DINC + t] = (bf16)acc;
}

// LayerNorm over 512 features (fp32 in, fp32 out)
__global__ __launch_bounds__(256) void layernorm512(
    const float* __restrict__ cbuf, const float* __restrict__ g,
    const float* __restrict__ b, float* __restrict__ out)
{
    const int r = blockIdx.x;
    const int t = threadIdx.x;
    float2 v = *(const float2*)&cbuf[(size_t)r * HIDC + t * 2];
    float s = v.x + v.y;
    float q = v.x * v.x + v.y * v.y;
    for (int o = 1; o < 64; o <<= 1) {
        s += __shfl_xor(s, o);
        q += __shfl_xor(q, o);
    }
    __shared__ float ls[4], lq[4];
    int w = t >> 6;
    if ((t & 63) == 0) { ls[w] = s; lq[w] = q; }
    __syncthreads();
    s = ls[0] + ls[1] + ls[2] + ls[3];
    q = lq[0] + lq[1] + lq[2] + lq[3];
    float mu  = s * (1.0f / 512.0f);
    float var = q * (1.0f / 512.0f) - mu * mu;
    float rs  = rsqrtf(var + 1e-5f);
    int c0 = t * 2;
    out[(size_t)r * HIDC + c0]     = (v.x - mu) * rs * g[c0]     + b[c0];
    out[(size_t)r * HIDC + c0 + 1] = (v.y - mu) * rs * g[c0 + 1] + b[c0 + 1];
}

// ---------------------------------------------------------------------------
extern "C" void kernel_launch(void* const* d_in, const int* in_sizes, int n_in,
                              void* d_out, int out_size, void* d_ws, size_t ws_size,
                              hipStream_t stream)
{
    const float* x      = (const float*)d_in[0];
    const float* W_l    = (const float*)d_in[1];
    const float* W_r    = (const float*)d_in[2];
    const float* att    = (const float*)d_in[3];
    const float* b_gat  = (const float*)d_in[4];
    const float* gin_W1 = (const float*)d_in[5];
    const float* gin_b1 = (const float*)d_in[6];
    const float* gin_W2 = (const float*)d_in[7];
    const float* gin_b2 = (const float*)d_in[8];
    const float* fus_W  = (const float*)d_in[9];
    const float* fus_b  = (const float*)d_in[10];
    const float* ln_g   = (const float*)d_in[11];
    const float* ln_b   = (const float*)d_in[12];
    const int*   eidx   = (const int*)d_in[13];

    const int E = in_sizes[13] / 2;
    const int N = in_sizes[0] / DINC;  // 8192
    const int* src = eidx;
    const int* dst = eidx + E;

    char* ws = (char*)d_ws;
    size_t off = 0;
    auto alloc = [&](size_t bytes) -> void* {
        void* p = ws + off;
        off = (off + bytes + 255) & ~(size_t)255;
        return p;
    };
    bf16* xb     = (bf16*)alloc((size_t)N * DINC * 2);
    bf16* xlr    = (bf16*)alloc((size_t)N * HIDC * 2);
    bf16* Wlr_t  = (bf16*)alloc((size_t)512 * 256 * 2);
    bf16* W1t    = (bf16*)alloc((size_t)256 * 256 * 2);
    bf16* W2t    = (bf16*)alloc((size_t)256 * 256 * 2);
    bf16* Wft    = (bf16*)alloc((size_t)512 * 512 * 2);
    bf16* hbuf   = (bf16*)alloc((size_t)N * DINC * 2);
    bf16* gin1   = (bf16*)alloc((size_t)N * DINC * 2);
    bf16* cat    = (bf16*)alloc((size_t)N * HIDC * 2);
    float* cbuf  = (float*)alloc((size_t)N * HIDC * 4);
    int* cnt_dst = (int*)alloc((size_t)N * 4);          // cnt_dst+cnt_src contiguous
    int* cnt_src = (int*)alloc((size_t)N * 4);
    int* off_dst = (int*)alloc((size_t)(N + 1) * 4);
    int* cur_dst = (int*)alloc((size_t)N * 4);
    int* off_src = (int*)alloc((size_t)(N + 1) * 4);
    int* cur_src = (int*)alloc((size_t)N * 4);
    int* csr_src = (int*)alloc((size_t)E * 4);
    int* csr_gin = (int*)alloc((size_t)E * 4);
    unsigned char* flags  = (unsigned char*)alloc((size_t)E);
    unsigned int*  bitmap = (unsigned int*)alloc((size_t)N * (size_t)N / 8);

    hipMemsetAsync(cnt_dst, 0, (size_t)N * 8, stream);               // both cnt arrays
    hipMemsetAsync(bitmap, 0, (size_t)N * (size_t)N / 8, stream);

    // weight transposes + x conversion
    prep<<<dim3(1024, 6), 256, 0, stream>>>(W_l, W_r, gin_W1, gin_W2, fus_W, x,
                                            Wlr_t, W1t, W2t, Wft, xb);

    // CSR build
    build_hist<<<(E + 255) / 256, 256, 0, stream>>>(src, dst, E, N, cnt_dst, cnt_src, bitmap, flags);
    scan_both<<<2, 1024, 0, stream>>>(cnt_dst, off_dst, cur_dst, cnt_src, off_src, cur_src);
    scatter_edges<<<(E + 255) / 256, 256, 0, stream>>>(src, dst, E, cur_dst, cur_src, flags, csr_src, csr_gin);

    // xlr = x @ [W_l | W_r]  (bf16 MFMA)
    gemm_mfma<0, 1><<<dim3(4, 64), 256, 0, stream>>>(xb, Wlr_t, nullptr, xlr, 256, HIDC, 0);

    // GIN aggregate + GAT fused
    gin_aggregate<<<N, 256, 0, stream>>>(xb, csr_gin, off_src, hbuf);
    gat_fused<<<N, 256, 0, stream>>>(xlr, csr_src, off_dst, att, b_gat, cat);

    // GIN MLP
    gemm_mfma<1, 1><<<dim3(2, 64), 256, 0, stream>>>(hbuf, W1t, gin_b1, gin1, 256, DINC, 0);
    gemm_mfma<0, 1><<<dim3(2, 64), 256, 0, stream>>>(gin1, W2t, gin_b2, cat, 256, HIDC, 256);

    // fusion GEMM (relu) -> fp32, then LayerNorm
    gemm_mfma<1, 0><<<dim3(4, 64), 256, 0, stream>>>(cat, Wft, fus_b, cbuf, 512, HIDC, 0);
    layernorm512<<<N, 256, 0, stream>>>(cbuf, ln_g, ln_b, (float*)d_out);

    (void)n_in; (void)out_size; (void)ws_size;
}

// Round 3
// 211.209 us; speedup vs baseline: 2.2978x; 1.3197x over previous
//
#include <hip/hip_runtime.h>

typedef __bf16 bf16;
typedef __attribute__((ext_vector_type(8))) __bf16 bf16x8;
typedef __attribute__((ext_vector_type(4))) float f32x4;

#define DINC 256
#define HIDC 512
#define MAXE 512   // max (deg+1) handled by the fast GAT path

__device__ __forceinline__ float lrelu02(float v) { return v > 0.0f ? v : 0.2f * v; }

__device__ __forceinline__ void gload_lds16(const void* g, void* l) {
    __builtin_amdgcn_global_load_lds(
        (const __attribute__((address_space(1))) unsigned int*)g,
        (__attribute__((address_space(3))) unsigned int*)l, 16, 0, 0);
}

// ---------------------------------------------------------------------------
// bf16 MFMA GEMM, 128x128 tile, BK=32, m97 2-barrier structure.
// A: [M][K] bf16 row-major. Bt: [N][K] bf16 (pre-transposed weights).
// C[row][col_off + col] = act(A@B + bias). 256 thr = 4 waves, wave = 64x64.
// ---------------------------------------------------------------------------
template<int RELU, int OUTBF16>
__global__ __launch_bounds__(256) void gemm_mfma(
    const bf16* __restrict__ A, const bf16* __restrict__ Bt,
    const float* __restrict__ bias, void* __restrict__ Cout,
    int K, int ldc, int col_off)
{
    __shared__ bf16 As[128 * 32];
    __shared__ bf16 Bs[128 * 32];
    const int t = threadIdx.x;
    const int w = t >> 6, lane = t & 63;
    const long brow = (long)blockIdx.y * 128;
    const long bcol = (long)blockIdx.x * 128;
    const int wr = (w >> 1) * 64, wc = (w & 1) * 64;
    const int fr = lane & 15, half = lane >> 4;
    const int srow = lane >> 2;
    const int skof = (lane & 3) * 8;

    f32x4 acc[4][4] = {};

    for (int k0 = 0; k0 < K; k0 += 32) {
        __syncthreads();
#pragma unroll
        for (int c2 = 0; c2 < 2; ++c2) {
            const int c = w + c2 * 4;
            const int row = c * 16 + srow;
            gload_lds16(A  + (brow + row) * K + k0 + skof, &As[c * 512]);
            gload_lds16(Bt + (bcol + row) * K + k0 + skof, &Bs[c * 512]);
        }
        __syncthreads();
        bf16x8 af[4], bfr[4];
#pragma unroll
        for (int i = 0; i < 4; ++i)
            af[i] = *(const bf16x8*)&As[(wr + i * 16 + fr) * 32 + half * 8];
#pragma unroll
        for (int j = 0; j < 4; ++j)
            bfr[j] = *(const bf16x8*)&Bs[(wc + j * 16 + fr) * 32 + half * 8];
#pragma unroll
        for (int i = 0; i < 4; ++i)
#pragma unroll
            for (int j = 0; j < 4; ++j)
                acc[i][j] = __builtin_amdgcn_mfma_f32_16x16x32_bf16(
                    af[i], bfr[j], acc[i][j], 0, 0, 0);
    }

#pragma unroll
    for (int i = 0; i < 4; ++i) {
#pragma unroll
        for (int j = 0; j < 4; ++j) {
            const long gcol = bcol + wc + j * 16 + fr;
            const float bv = bias ? bias[gcol] : 0.0f;
#pragma unroll
            for (int v = 0; v < 4; ++v) {
                const long grow = brow + wr + i * 16 + half * 4 + v;
                float val = acc[i][j][v] + bv;
                if (RELU) val = fmaxf(val, 0.0f);
                if (OUTBF16) ((bf16*)Cout)[grow * ldc + col_off + gcol] = (bf16)val;
                else         ((float*)Cout)[grow * ldc + col_off + gcol] = val;
            }
        }
    }
}

// ---------------------------------------------------------------------------
// prep: jobs 0-4 transpose+convert weights to bf16 [N][K]; job 5 converts x.
// ---------------------------------------------------------------------------
__global__ __launch_bounds__(256) void prep(
    const float* __restrict__ W_l, const float* __restrict__ W_r,
    const float* __restrict__ gin_W1, const float* __restrict__ gin_W2,
    const float* __restrict__ fus_W, const float* __restrict__ x,
    bf16* __restrict__ Wlr_t, bf16* __restrict__ W1t, bf16* __restrict__ W2t,
    bf16* __restrict__ Wft, bf16* __restrict__ xb)
{
    const int job = blockIdx.y;
    const int idx = blockIdx.x * 256 + threadIdx.x;
    if (job == 5) {
        const float4* xv = (const float4*)x;
        float4 a = xv[(size_t)idx * 2], b = xv[(size_t)idx * 2 + 1];
        bf16x8 o;
        o[0] = (bf16)a.x; o[1] = (bf16)a.y; o[2] = (bf16)a.z; o[3] = (bf16)a.w;
        o[4] = (bf16)b.x; o[5] = (bf16)b.y; o[6] = (bf16)b.z; o[7] = (bf16)b.w;
        *(bf16x8*)&xb[(size_t)idx * 8] = o;
        return;
    }
    const float* src; bf16* dst; int K, Nc;
    switch (job) {
        case 0: src = W_l;    dst = Wlr_t;             K = 256; Nc = 256; break;
        case 1: src = W_r;    dst = Wlr_t + 256 * 256; K = 256; Nc = 256; break;
        case 2: src = gin_W1; dst = W1t;               K = 256; Nc = 256; break;
        case 3: src = gin_W2; dst = W2t;               K = 256; Nc = 256; break;
        default: src = fus_W; dst = Wft;               K = 512; Nc = 512; break;
    }
    if (idx >= K * Nc) return;
    const int n = idx / K, k = idx % K;
    dst[idx] = (bf16)src[(size_t)k * Nc + n];
}

// ---------------------------------------------------------------------------
// CSR build
// ---------------------------------------------------------------------------
__global__ __launch_bounds__(256) void build_hist(
    const int* __restrict__ src, const int* __restrict__ dst, int E, int N,
    int* __restrict__ cnt_dst, int* __restrict__ cnt_src,
    unsigned int* __restrict__ bitmap, unsigned char* __restrict__ flags)
{
    int e = blockIdx.x * 256 + threadIdx.x;
    if (e >= E) return;
    int s = src[e], d = dst[e];
    atomicAdd(&cnt_dst[d], 1);
    unsigned int key  = (unsigned int)s * (unsigned int)N + (unsigned int)d;
    unsigned int word = key >> 5;
    unsigned int bit  = 1u << (key & 31u);
    unsigned int old  = atomicOr(&bitmap[word], bit);
    int own = (old & bit) == 0u;
    flags[e] = (unsigned char)own;
    if (own) atomicAdd(&cnt_src[s], 1);
}

__global__ __launch_bounds__(1024) void scan_both(
    const int* __restrict__ cnt_dst, int* __restrict__ off_dst, int* __restrict__ cur_dst,
    const int* __restrict__ cnt_src, int* __restrict__ off_src, int* __restrict__ cur_src)
{
    const int* cnt = blockIdx.x ? cnt_src : cnt_dst;
    int* off = blockIdx.x ? off_src : off_dst;
    int* cur = blockIdx.x ? cur_src : cur_dst;
    __shared__ int lds[1024];
    const int t = threadIdx.x;
    const int base = t * 8;
    int v[8]; int s = 0;
#pragma unroll
    for (int j = 0; j < 8; ++j) { v[j] = cnt[base + j]; s += v[j]; }
    lds[t] = s;
    __syncthreads();
    int mine = s;
    for (int o = 1; o < 1024; o <<= 1) {
        int add = (t >= o) ? lds[t - o] : 0;
        __syncthreads();
        lds[t] += add;
        __syncthreads();
    }
    int run = lds[t] - mine;
#pragma unroll
    for (int j = 0; j < 8; ++j) { off[base + j] = run; cur[base + j] = run; run += v[j]; }
    if (t == 1023) off[8192] = run;
}

__global__ __launch_bounds__(256) void scatter_edges(
    const int* __restrict__ src, const int* __restrict__ dst, int E,
    int* __restrict__ cur_dst, int* __restrict__ cur_src,
    const unsigned char* __restrict__ flags,
    int* __restrict__ csr_src, int* __restrict__ csr_gin)
{
    int e = blockIdx.x * 256 + threadIdx.x;
    if (e >= E) return;
    int s = src[e], d = dst[e];
    int p = atomicAdd(&cur_dst[d], 1);
    csr_src[p] = s;
    if (flags[e]) {
        int q = atomicAdd(&cur_src[s], 1);
        csr_gin[q] = d;
    }
}

// ---------------------------------------------------------------------------
// Fused GATv2 v2: block per dst node, two-phase, batched 8-edge score pass.
// xlr: [N][512] bf16 (cols 0-255 = xl, 256-511 = xr). Writes cat[:,0:256].
// ---------------------------------------------------------------------------
__global__ __launch_bounds__(256) void gat_fused(
    const bf16* __restrict__ xlr, const int* __restrict__ csr_src,
    const int* __restrict__ off_dst, const float* __restrict__ att,
    const float* __restrict__ b_gat, bf16* __restrict__ cat)
{
    __shared__ float sc[4 * MAXE];   // [head][jj]  (exp-weights after phase 2)
    __shared__ float sden[4];
    const int d = blockIdx.x, t = threadIdx.x;
    const int beg = off_dst[d];
    const int deg = off_dst[d + 1] - beg;
    const int cnt = deg + 1;         // + self-loop (index deg)

    if (cnt <= MAXE) {
        // ---- phase 1: scores, 8 edges at a time ----
        const int e8 = t >> 5;          // edge slot 0..7
        const int g  = t & 31;          // feature group (8 feats each)
        const int h8 = g >> 3;          // head of this group
        float xr8[8], at8[8];
        {
            bf16x8 xv = *(const bf16x8*)&xlr[(size_t)d * HIDC + 256 + g * 8];
#pragma unroll
            for (int f = 0; f < 8; ++f) xr8[f] = (float)xv[f];
            float4 a0 = *(const float4*)&att[g * 8];
            float4 a1 = *(const float4*)&att[g * 8 + 4];
            at8[0] = a0.x; at8[1] = a0.y; at8[2] = a0.z; at8[3] = a0.w;
            at8[4] = a1.x; at8[5] = a1.y; at8[6] = a1.z; at8[7] = a1.w;
        }
        for (int base = 0; base < cnt; base += 8) {
            const int jj = base + e8;
            int s = d;
            if (jj < deg) s = csr_src[beg + jj];
            bf16x8 xv = *(const bf16x8*)&xlr[(size_t)s * HIDC + g * 8];
            float p = 0.0f;
#pragma unroll
            for (int f = 0; f < 8; ++f)
                p += lrelu02((float)xv[f] + xr8[f]) * at8[f];
            p += __shfl_xor(p, 1);
            p += __shfl_xor(p, 2);
            p += __shfl_xor(p, 4);
            if (jj < cnt && (g & 7) == 0) sc[h8 * MAXE + jj] = p;
        }
        __syncthreads();
        // ---- phase 2: per-head max + exp weights + denom ----
        {
            const int h = t >> 6, k = t & 63;
            float m = -1e30f;
            for (int jj = k; jj < cnt; jj += 64) m = fmaxf(m, sc[h * MAXE + jj]);
#pragma unroll
            for (int o = 1; o < 64; o <<= 1) m = fmaxf(m, __shfl_xor(m, o));
            float ds = 0.0f;
            for (int jj = k; jj < cnt; jj += 64) {
                float wgt = __expf(sc[h * MAXE + jj] - m);
                sc[h * MAXE + jj] = wgt;
                ds += wgt;
            }
#pragma unroll
            for (int o = 1; o < 64; o <<= 1) ds += __shfl_xor(ds, o);
            if (k == 0) sden[h] = ds;
        }
        __syncthreads();
        // ---- phase 3: weighted aggregation, thread = feature, unroll x4 ----
        const int h = t >> 6;
        const float* wrow = &sc[h * MAXE];
        float acc = 0.0f;
        int jj = 0;
        for (; jj + 4 <= cnt; jj += 4) {
            const int s0 = (jj     < deg) ? csr_src[beg + jj]     : d;
            const int s1 = (jj + 1 < deg) ? csr_src[beg + jj + 1] : d;
            const int s2 = (jj + 2 < deg) ? csr_src[beg + jj + 2] : d;
            const int s3 = (jj + 3 < deg) ? csr_src[beg + jj + 3] : d;
            const float v0 = (float)xlr[(size_t)s0 * HIDC + t];
            const float v1 = (float)xlr[(size_t)s1 * HIDC + t];
            const float v2 = (float)xlr[(size_t)s2 * HIDC + t];
            const float v3 = (float)xlr[(size_t)s3 * HIDC + t];
            acc = fmaf(wrow[jj], v0, acc);
            acc = fmaf(wrow[jj + 1], v1, acc);
            acc = fmaf(wrow[jj + 2], v2, acc);
            acc = fmaf(wrow[jj + 3], v3, acc);
        }
        for (; jj < cnt; ++jj) {
            const int s = (jj < deg) ? csr_src[beg + jj] : d;
            acc = fmaf(wrow[jj], (float)xlr[(size_t)s * HIDC + t], acc);
        }
        cat[(size_t)d * HIDC + t] = (bf16)(acc / sden[h] + b_gat[t]);
        return;
    }

    // ---- fallback: serial online softmax (any degree) ----
    {
        const float attv = att[t];
        const float xrv = (float)xlr[(size_t)d * HIDC + 256 + t];
        const float xld = (float)xlr[(size_t)d * HIDC + t];
        float p = lrelu02(xld + xrv) * attv;
#pragma unroll
        for (int o = 1; o < 64; o <<= 1) p += __shfl_xor(p, o);
        float m = p, denom = 1.0f, acc = xld;
        for (int j = beg; j < beg + deg; ++j) {
            const int s = csr_src[j];
            const float xls = (float)xlr[(size_t)s * HIDC + t];
            float q = lrelu02(xls + xrv) * attv;
#pragma unroll
            for (int o = 1; o < 64; o <<= 1) q += __shfl_xor(q, o);
            if (q > m) {
                const float r = __expf(m - q);
                denom = denom * r + 1.0f;
                acc   = acc * r + xls;
                m = q;
            } else {
                const float wgt = __expf(q - m);
                denom += wgt;
                acc   += wgt * xls;
            }
        }
        cat[(size_t)d * HIDC + t] = (bf16)(acc / denom + b_gat[t]);
    }
}

// GIN aggregation, unroll x4: h[i] = x[i] + sum over deduped out-edges x[dst]
__global__ __launch_bounds__(256) void gin_aggregate(
    const bf16* __restrict__ xb, const int* __restrict__ csr_gin,
    const int* __restrict__ off_src, bf16* __restrict__ hbuf)
{
    const int i = blockIdx.x, t = threadIdx.x;
    const int beg = off_src[i], end = off_src[i + 1];
    float acc = (float)xb[(size_t)i * DINC + t];
    int j = beg;
    for (; j + 4 <= end; j += 4) {
        const int s0 = csr_gin[j], s1 = csr_gin[j + 1];
        const int s2 = csr_gin[j + 2], s3 = csr_gin[j + 3];
        const float v0 = (float)xb[(size_t)s0 * DINC + t];
        const float v1 = (float)xb[(size_t)s1 * DINC + t];
        const float v2 = (float)xb[(size_t)s2 * DINC + t];
        const float v3 = (float)xb[(size_t)s3 * DINC + t];
        acc += (v0 + v1) + (v2 + v3);
    }
    for (; j < end; ++j)
        acc += (float)xb[(size_t)csr_gin[j] * DINC + t];
    hbuf[(size_t)i * DINC + t] = (bf16)acc;
}

// LayerNorm over 512 features (fp32 in, fp32 out)
__global__ __launch_bounds__(256) void layernorm512(
    const float* __restrict__ cbuf, const float* __restrict__ g,
    const float* __restrict__ b, float* __restrict__ out)
{
    const int r = blockIdx.x;
    const int t = threadIdx.x;
    float2 v = *(const float2*)&cbuf[(size_t)r * HIDC + t * 2];
    float s = v.x + v.y;
    float q = v.x * v.x + v.y * v.y;
    for (int o = 1; o < 64; o <<= 1) {
        s += __shfl_xor(s, o);
        q += __shfl_xor(q, o);
    }
    __shared__ float ls[4], lq[4];
    int w = t >> 6;
    if ((t & 63) == 0) { ls[w] = s; lq[w] = q; }
    __syncthreads();
    s = ls[0] + ls[1] + ls[2] + ls[3];
    q = lq[0] + lq[1] + lq[2] + lq[3];
    float mu  = s * (1.0f / 512.0f);
    float var = q * (1.0f / 512.0f) - mu * mu;
    float rs  = rsqrtf(var + 1e-5f);
    int c0 = t * 2;
    out[(size_t)r * HIDC + c0]     = (v.x - mu) * rs * g[c0]     + b[c0];
    out[(size_t)r * HIDC + c0 + 1] = (v.y - mu) * rs * g[c0 + 1] + b[c0 + 1];
}

// ---------------------------------------------------------------------------
extern "C" void kernel_launch(void* const* d_in, const int* in_sizes, int n_in,
                              void* d_out, int out_size, void* d_ws, size_t ws_size,
                              hipStream_t stream)
{
    const float* x      = (const float*)d_in[0];
    const float* W_l    = (const float*)d_in[1];
    const float* W_r    = (const float*)d_in[2];
    const float* att    = (const float*)d_in[3];
    const float* b_gat  = (const float*)d_in[4];
    const float* gin_W1 = (const float*)d_in[5];
    const float* gin_b1 = (const float*)d_in[6];
    const float* gin_W2 = (const float*)d_in[7];
    const float* gin_b2 = (const float*)d_in[8];
    const float* fus_W  = (const float*)d_in[9];
    const float* fus_b  = (const float*)d_in[10];
    const float* ln_g   = (const float*)d_in[11];
    const float* ln_b   = (const float*)d_in[12];
    const int*   eidx   = (const int*)d_in[13];

    const int E = in_sizes[13] / 2;
    const int N = in_sizes[0] / DINC;  // 8192
    const int* src = eidx;
    const int* dst = eidx + E;

    char* ws = (char*)d_ws;
    size_t off = 0;
    auto alloc = [&](size_t bytes) -> void* {
        void* p = ws + off;
        off = (off + bytes + 255) & ~(size_t)255;
        return p;
    };
    bf16* xb     = (bf16*)alloc((size_t)N * DINC * 2);
    bf16* xlr    = (bf16*)alloc((size_t)N * HIDC * 2);
    bf16* Wlr_t  = (bf16*)alloc((size_t)512 * 256 * 2);
    bf16* W1t    = (bf16*)alloc((size_t)256 * 256 * 2);
    bf16* W2t    = (bf16*)alloc((size_t)256 * 256 * 2);
    bf16* Wft    = (bf16*)alloc((size_t)512 * 512 * 2);
    bf16* hbuf   = (bf16*)alloc((size_t)N * DINC * 2);
    bf16* gin1   = (bf16*)alloc((size_t)N * DINC * 2);
    bf16* cat    = (bf16*)alloc((size_t)N * HIDC * 2);
    float* cbuf  = (float*)alloc((size_t)N * HIDC * 4);
    int* cnt_dst = (int*)alloc((size_t)N * 4);
    int* cnt_src = (int*)alloc((size_t)N * 4);
    int* off_dst = (int*)alloc((size_t)(N + 1) * 4);
    int* cur_dst = (int*)alloc((size_t)N * 4);
    int* off_src = (int*)alloc((size_t)(N + 1) * 4);
    int* cur_src = (int*)alloc((size_t)N * 4);
    int* csr_src = (int*)alloc((size_t)E * 4);
    int* csr_gin = (int*)alloc((size_t)E * 4);
    unsigned char* flags  = (unsigned char*)alloc((size_t)E);
    unsigned int*  bitmap = (unsigned int*)alloc((size_t)N * (size_t)N / 8);

    hipMemsetAsync(cnt_dst, 0, (size_t)N * 8, stream);
    hipMemsetAsync(bitmap, 0, (size_t)N * (size_t)N / 8, stream);

    prep<<<dim3(1024, 6), 256, 0, stream>>>(W_l, W_r, gin_W1, gin_W2, fus_W, x,
                                            Wlr_t, W1t, W2t, Wft, xb);

    build_hist<<<(E + 255) / 256, 256, 0, stream>>>(src, dst, E, N, cnt_dst, cnt_src, bitmap, flags);
    scan_both<<<2, 1024, 0, stream>>>(cnt_dst, off_dst, cur_dst, cnt_src, off_src, cur_src);
    scatter_edges<<<(E + 255) / 256, 256, 0, stream>>>(src, dst, E, cur_dst, cur_src, flags, csr_src, csr_gin);

    // xlr = x @ [W_l | W_r]  (bf16 MFMA)
    gemm_mfma<0, 1><<<dim3(4, 64), 256, 0, stream>>>(xb, Wlr_t, nullptr, xlr, 256, HIDC, 0);

    gin_aggregate<<<N, 256, 0, stream>>>(xb, csr_gin, off_src, hbuf);
    gat_fused<<<N, 256, 0, stream>>>(xlr, csr_src, off_dst, att, b_gat, cat);

    gemm_mfma<1, 1><<<dim3(2, 64), 256, 0, stream>>>(hbuf, W1t, gin_b1, gin1, 256, DINC, 0);
    gemm_mfma<0, 1><<<dim3(2, 64), 256, 0, stream>>>(gin1, W2t, gin_b2, cat, 256, HIDC, 256);

    gemm_mfma<1, 0><<<dim3(4, 64), 256, 0, stream>>>(cat, Wft, fus_b, cbuf, 512, HIDC, 0);
    layernorm512<<<N, 256, 0, stream>>>(cbuf, ln_g, ln_b, (float*)d_out);

    (void)n_in; (void)out_size; (void)ws_size;
}

// Round 4
// 195.902 us; speedup vs baseline: 2.4774x; 1.0781x over previous
//
#include <hip/hip_runtime.h>

typedef __bf16 bf16;
typedef __attribute__((ext_vector_type(8))) __bf16 bf16x8;
typedef __attribute__((ext_vector_type(4))) float f32x4;

#define DINC 256
#define HIDC 512
#define CAP  48    // fast-path max (deg+1): rows cached in LDS
#define MAXE 512   // mid-path max (deg+1): scores in LDS, global gather

__device__ __forceinline__ float lrelu02(float v) { return fmaxf(v, 0.2f * v); }

__device__ __forceinline__ void gload_lds16(const void* g, void* l) {
    __builtin_amdgcn_global_load_lds(
        (const __attribute__((address_space(1))) unsigned int*)g,
        (__attribute__((address_space(3))) unsigned int*)l, 16, 0, 0);
}

// ---------------------------------------------------------------------------
// bf16 MFMA GEMM, 64x64 tile, BK=32. 256 thr = 4 waves, wave = 32x32 quadrant.
// A: [M][K] bf16 row-major. Bt: [N][K] bf16 (pre-transposed weights).
// Small-GEMM-friendly: grid = (N/64, M/64) gives 2-4 blocks/CU at our shapes.
// ---------------------------------------------------------------------------
template<int RELU, int OUTBF16>
__global__ __launch_bounds__(256) void gemm64(
    const bf16* __restrict__ A, const bf16* __restrict__ Bt,
    const float* __restrict__ bias, void* __restrict__ Cout,
    int K, int ldc, int col_off)
{
    __shared__ bf16 As[64 * 32];
    __shared__ bf16 Bs[64 * 32];
    const int t = threadIdx.x;
    const int w = t >> 6, lane = t & 63;
    const long brow = (long)blockIdx.y * 64;
    const long bcol = (long)blockIdx.x * 64;
    const int wr = (w >> 1) * 32, wc = (w & 1) * 32;
    const int fr = lane & 15, half = lane >> 4;

    // staging: lane covers row t>>2, k-offset (t&3)*8; LDS linear = t*16B
    const bf16* Ag = A  + (size_t)(brow + (t >> 2)) * K + (t & 3) * 8;
    const bf16* Bg = Bt + (size_t)(bcol + (t >> 2)) * K + (t & 3) * 8;

    f32x4 acc[2][2] = {};

    for (int k0 = 0; k0 < K; k0 += 32) {
        __syncthreads();
        gload_lds16(Ag + k0, &As[t * 8]);
        gload_lds16(Bg + k0, &Bs[t * 8]);
        __syncthreads();
        bf16x8 af[2], bfr[2];
#pragma unroll
        for (int i = 0; i < 2; ++i)
            af[i] = *(const bf16x8*)&As[(wr + i * 16 + fr) * 32 + half * 8];
#pragma unroll
        for (int j = 0; j < 2; ++j)
            bfr[j] = *(const bf16x8*)&Bs[(wc + j * 16 + fr) * 32 + half * 8];
#pragma unroll
        for (int i = 0; i < 2; ++i)
#pragma unroll
            for (int j = 0; j < 2; ++j)
                acc[i][j] = __builtin_amdgcn_mfma_f32_16x16x32_bf16(
                    af[i], bfr[j], acc[i][j], 0, 0, 0);
    }

#pragma unroll
    for (int i = 0; i < 2; ++i) {
#pragma unroll
        for (int j = 0; j < 2; ++j) {
            const long gcol = bcol + wc + j * 16 + fr;
            const float bv = bias ? bias[gcol] : 0.0f;
#pragma unroll
            for (int v = 0; v < 4; ++v) {
                const long grow = brow + wr + i * 16 + half * 4 + v;
                float val = acc[i][j][v] + bv;
                if (RELU) val = fmaxf(val, 0.0f);
                if (OUTBF16) ((bf16*)Cout)[grow * ldc + col_off + gcol] = (bf16)val;
                else         ((float*)Cout)[grow * ldc + col_off + gcol] = val;
            }
        }
    }
}

// ---------------------------------------------------------------------------
// Coalesced weight transpose+convert: src [K][Nc] f32 -> dst [Nc][K] bf16.
// ---------------------------------------------------------------------------
__global__ __launch_bounds__(256) void transpose_w(
    const float* __restrict__ W_l, const float* __restrict__ W_r,
    const float* __restrict__ gin_W1, const float* __restrict__ gin_W2,
    const float* __restrict__ fus_W,
    bf16* __restrict__ Wlr_t, bf16* __restrict__ W1t, bf16* __restrict__ W2t,
    bf16* __restrict__ Wft)
{
    const float* src; bf16* dst; int K, Nc;
    switch (blockIdx.z) {
        case 0: src = W_l;    dst = Wlr_t;             K = 256; Nc = 256; break;
        case 1: src = W_r;    dst = Wlr_t + 256 * 256; K = 256; Nc = 256; break;
        case 2: src = gin_W1; dst = W1t;               K = 256; Nc = 256; break;
        case 3: src = gin_W2; dst = W2t;               K = 256; Nc = 256; break;
        default: src = fus_W; dst = Wft;               K = 512; Nc = 512; break;
    }
    const int bn = blockIdx.x * 32, bk = blockIdx.y * 32;
    if (bn >= Nc || bk >= K) return;
    __shared__ float tile[32][33];
    const int tx = threadIdx.x & 31, ty = threadIdx.x >> 5;
#pragma unroll
    for (int r = 0; r < 32; r += 8)
        tile[ty + r][tx] = src[(size_t)(bk + ty + r) * Nc + bn + tx];
    __syncthreads();
#pragma unroll
    for (int r = 0; r < 32; r += 8)
        dst[(size_t)(bn + ty + r) * K + bk + tx] = (bf16)tile[tx][ty + r];
}

__global__ __launch_bounds__(256) void convert_x(
    const float* __restrict__ x, bf16* __restrict__ xb)
{
    const int idx = blockIdx.x * 256 + threadIdx.x;
    const float4* xv = (const float4*)x;
    float4 a = xv[(size_t)idx * 2], b = xv[(size_t)idx * 2 + 1];
    bf16x8 o;
    o[0] = (bf16)a.x; o[1] = (bf16)a.y; o[2] = (bf16)a.z; o[3] = (bf16)a.w;
    o[4] = (bf16)b.x; o[5] = (bf16)b.y; o[6] = (bf16)b.z; o[7] = (bf16)b.w;
    *(bf16x8*)&xb[(size_t)idx * 8] = o;
}

// ---------------------------------------------------------------------------
// CSR build
// ---------------------------------------------------------------------------
__global__ __launch_bounds__(256) void build_hist(
    const int* __restrict__ src, const int* __restrict__ dst, int E, int N,
    int* __restrict__ cnt_dst, int* __restrict__ cnt_src,
    unsigned int* __restrict__ bitmap, unsigned char* __restrict__ flags)
{
    int e = blockIdx.x * 256 + threadIdx.x;
    if (e >= E) return;
    int s = src[e], d = dst[e];
    atomicAdd(&cnt_dst[d], 1);
    unsigned int key  = (unsigned int)s * (unsigned int)N + (unsigned int)d;
    unsigned int word = key >> 5;
    unsigned int bit  = 1u << (key & 31u);
    unsigned int old  = atomicOr(&bitmap[word], bit);
    int own = (old & bit) == 0u;
    flags[e] = (unsigned char)own;
    if (own) atomicAdd(&cnt_src[s], 1);
}

__global__ __launch_bounds__(1024) void scan_both(
    const int* __restrict__ cnt_dst, int* __restrict__ off_dst, int* __restrict__ cur_dst,
    const int* __restrict__ cnt_src, int* __restrict__ off_src, int* __restrict__ cur_src)
{
    const int* cnt = blockIdx.x ? cnt_src : cnt_dst;
    int* off = blockIdx.x ? off_src : off_dst;
    int* cur = blockIdx.x ? cur_src : cur_dst;
    __shared__ int lds[1024];
    const int t = threadIdx.x;
    const int base = t * 8;
    int v[8]; int s = 0;
#pragma unroll
    for (int j = 0; j < 8; ++j) { v[j] = cnt[base + j]; s += v[j]; }
    lds[t] = s;
    __syncthreads();
    int mine = s;
    for (int o = 1; o < 1024; o <<= 1) {
        int add = (t >= o) ? lds[t - o] : 0;
        __syncthreads();
        lds[t] += add;
        __syncthreads();
    }
    int run = lds[t] - mine;
#pragma unroll
    for (int j = 0; j < 8; ++j) { off[base + j] = run; cur[base + j] = run; run += v[j]; }
    if (t == 1023) off[8192] = run;
}

__global__ __launch_bounds__(256) void scatter_edges(
    const int* __restrict__ src, const int* __restrict__ dst, int E,
    int* __restrict__ cur_dst, int* __restrict__ cur_src,
    const unsigned char* __restrict__ flags,
    int* __restrict__ csr_src, int* __restrict__ csr_gin)
{
    int e = blockIdx.x * 256 + threadIdx.x;
    if (e >= E) return;
    int s = src[e], d = dst[e];
    int p = atomicAdd(&cur_dst[d], 1);
    csr_src[p] = s;
    if (flags[e]) {
        int q = atomicAdd(&cur_src[s], 1);
        csr_gin[q] = d;
    }
}

// ---------------------------------------------------------------------------
// Fused GATv2 v3: block per dst node.
//  fast path (cnt<=CAP): score pass caches neighbor xl rows in LDS; the
//  aggregation pass reads LDS (no second global gather).
//  mid path (cnt<=MAXE): scores in LDS (reusing row buffer), global gather.
//  serial path: online softmax, any degree.
// ---------------------------------------------------------------------------
__global__ __launch_bounds__(256) void gat_fused(
    const bf16* __restrict__ xlr, const int* __restrict__ csr_src,
    const int* __restrict__ off_dst, const float* __restrict__ att,
    const float* __restrict__ b_gat, bf16* __restrict__ cat)
{
    __shared__ __align__(16) char lds_raw[CAP * 512];   // bf16 rows[CAP][256] / float ssc[4][MAXE]
    __shared__ float sc[4 * CAP];
    __shared__ float sden[4];
    bf16* rows = (bf16*)lds_raw;
    float* ssc = (float*)lds_raw;

    const int d = blockIdx.x, t = threadIdx.x;
    const int beg = off_dst[d];
    const int deg = off_dst[d + 1] - beg;
    const int cnt = deg + 1;

    if (cnt <= CAP) {
        // ---- phase 1: scores + row cache, 8 edges at a time ----
        const int e8 = t >> 5, g = t & 31, h8 = g >> 3;
        float xr8[8], at8[8];
        {
            bf16x8 xv = *(const bf16x8*)&xlr[(size_t)d * HIDC + 256 + g * 8];
#pragma unroll
            for (int f = 0; f < 8; ++f) xr8[f] = (float)xv[f];
            float4 a0 = *(const float4*)&att[g * 8];
            float4 a1 = *(const float4*)&att[g * 8 + 4];
            at8[0] = a0.x; at8[1] = a0.y; at8[2] = a0.z; at8[3] = a0.w;
            at8[4] = a1.x; at8[5] = a1.y; at8[6] = a1.z; at8[7] = a1.w;
        }
        for (int base = 0; base < cnt; base += 8) {
            const int jj = base + e8;
            int s = d;
            if (jj < deg) s = csr_src[beg + jj];
            bf16x8 xv = *(const bf16x8*)&xlr[(size_t)s * HIDC + g * 8];
            float p = 0.0f;
#pragma unroll
            for (int f = 0; f < 8; ++f)
                p += lrelu02((float)xv[f] + xr8[f]) * at8[f];
            p += __shfl_xor(p, 1);
            p += __shfl_xor(p, 2);
            p += __shfl_xor(p, 4);
            if (jj < cnt) {
                *(bf16x8*)&rows[jj * 256 + g * 8] = xv;
                if ((g & 7) == 0) sc[h8 * CAP + jj] = p;
            }
        }
        __syncthreads();
        // ---- phase 2: per-head max + exp weights + denom (cnt <= 48 < 64) ----
        {
            const int h = t >> 6, k = t & 63;
            float m = (k < cnt) ? sc[h * CAP + k] : -1e30f;
#pragma unroll
            for (int o = 1; o < 64; o <<= 1) m = fmaxf(m, __shfl_xor(m, o));
            float ds = 0.0f;
            if (k < cnt) {
                ds = __expf(sc[h * CAP + k] - m);
                sc[h * CAP + k] = ds;
            }
#pragma unroll
            for (int o = 1; o < 64; o <<= 1) ds += __shfl_xor(ds, o);
            if (k == 0) sden[h] = ds;
        }
        __syncthreads();
        // ---- phase 3: weighted aggregation from LDS rows ----
        const int h = t >> 6;
        const float* wrow = &sc[h * CAP];
        float acc = 0.0f;
#pragma unroll 4
        for (int jj = 0; jj < cnt; ++jj)
            acc = fmaf(wrow[jj], (float)rows[jj * 256 + t], acc);
        cat[(size_t)d * HIDC + t] = (bf16)(acc / sden[h] + b_gat[t]);
        return;
    }

    if (cnt <= MAXE) {
        // ---- mid path: scores in LDS, re-gather for aggregation ----
        const int e8 = t >> 5, g = t & 31, h8 = g >> 3;
        float xr8[8], at8[8];
        {
            bf16x8 xv = *(const bf16x8*)&xlr[(size_t)d * HIDC + 256 + g * 8];
#pragma unroll
            for (int f = 0; f < 8; ++f) xr8[f] = (float)xv[f];
            float4 a0 = *(const float4*)&att[g * 8];
            float4 a1 = *(const float4*)&att[g * 8 + 4];
            at8[0] = a0.x; at8[1] = a0.y; at8[2] = a0.z; at8[3] = a0.w;
            at8[4] = a1.x; at8[5] = a1.y; at8[6] = a1.z; at8[7] = a1.w;
        }
        for (int base = 0; base < cnt; base += 8) {
            const int jj = base + e8;
            int s = d;
            if (jj < deg) s = csr_src[beg + jj];
            bf16x8 xv = *(const bf16x8*)&xlr[(size_t)s * HIDC + g * 8];
            float p = 0.0f;
#pragma unroll
            for (int f = 0; f < 8; ++f)
                p += lrelu02((float)xv[f] + xr8[f]) * at8[f];
            p += __shfl_xor(p, 1);
            p += __shfl_xor(p, 2);
            p += __shfl_xor(p, 4);
            if (jj < cnt && (g & 7) == 0) ssc[h8 * MAXE + jj] = p;
        }
        __syncthreads();
        {
            const int h = t >> 6, k = t & 63;
            float m = -1e30f;
            for (int jj = k; jj < cnt; jj += 64) m = fmaxf(m, ssc[h * MAXE + jj]);
#pragma unroll
            for (int o = 1; o < 64; o <<= 1) m = fmaxf(m, __shfl_xor(m, o));
            float ds = 0.0f;
            for (int jj = k; jj < cnt; jj += 64) {
                float wgt = __expf(ssc[h * MAXE + jj] - m);
                ssc[h * MAXE + jj] = wgt;
                ds += wgt;
            }
#pragma unroll
            for (int o = 1; o < 64; o <<= 1) ds += __shfl_xor(ds, o);
            if (k == 0) sden[h] = ds;
        }
        __syncthreads();
        const int h = t >> 6;
        const float* wrow = &ssc[h * MAXE];
        float acc = 0.0f;
        int jj = 0;
        for (; jj + 4 <= cnt; jj += 4) {
            const int s0 = (jj     < deg) ? csr_src[beg + jj]     : d;
            const int s1 = (jj + 1 < deg) ? csr_src[beg + jj + 1] : d;
            const int s2 = (jj + 2 < deg) ? csr_src[beg + jj + 2] : d;
            const int s3 = (jj + 3 < deg) ? csr_src[beg + jj + 3] : d;
            const float v0 = (float)xlr[(size_t)s0 * HIDC + t];
            const float v1 = (float)xlr[(size_t)s1 * HIDC + t];
            const float v2 = (float)xlr[(size_t)s2 * HIDC + t];
            const float v3 = (float)xlr[(size_t)s3 * HIDC + t];
            acc = fmaf(wrow[jj], v0, acc);
            acc = fmaf(wrow[jj + 1], v1, acc);
            acc = fmaf(wrow[jj + 2], v2, acc);
            acc = fmaf(wrow[jj + 3], v3, acc);
        }
        for (; jj < cnt; ++jj) {
            const int s = (jj < deg) ? csr_src[beg + jj] : d;
            acc = fmaf(wrow[jj], (float)xlr[(size_t)s * HIDC + t], acc);
        }
        cat[(size_t)d * HIDC + t] = (bf16)(acc / sden[h] + b_gat[t]);
        return;
    }

    // ---- serial fallback: online softmax, any degree ----
    {
        const float attv = att[t];
        const float xrv = (float)xlr[(size_t)d * HIDC + 256 + t];
        const float xld = (float)xlr[(size_t)d * HIDC + t];
        float p = lrelu02(xld + xrv) * attv;
#pragma unroll
        for (int o = 1; o < 64; o <<= 1) p += __shfl_xor(p, o);
        float m = p, denom = 1.0f, acc = xld;
        for (int j = beg; j < beg + deg; ++j) {
            const int s = csr_src[j];
            const float xls = (float)xlr[(size_t)s * HIDC + t];
            float q = lrelu02(xls + xrv) * attv;
#pragma unroll
            for (int o = 1; o < 64; o <<= 1) q += __shfl_xor(q, o);
            if (q > m) {
                const float r = __expf(m - q);
                denom = denom * r + 1.0f;
                acc   = acc * r + xls;
                m = q;
            } else {
                const float wgt = __expf(q - m);
                denom += wgt;
                acc   += wgt * xls;
            }
        }
        cat[(size_t)d * HIDC + t] = (bf16)(acc / denom + b_gat[t]);
    }
}

// GIN aggregation, unroll x8
__global__ __launch_bounds__(256) void gin_aggregate(
    const bf16* __restrict__ xb, const int* __restrict__ csr_gin,
    const int* __restrict__ off_src, bf16* __restrict__ hbuf)
{
    const int i = blockIdx.x, t = threadIdx.x;
    const int beg = off_src[i], end = off_src[i + 1];
    float acc = (float)xb[(size_t)i * DINC + t];
    int j = beg;
    for (; j + 8 <= end; j += 8) {
        float v[8];
#pragma unroll
        for (int u = 0; u < 8; ++u) {
            const int s = csr_gin[j + u];
            v[u] = (float)xb[(size_t)s * DINC + t];
        }
#pragma unroll
        for (int u = 0; u < 8; ++u) acc += v[u];
    }
    for (; j < end; ++j)
        acc += (float)xb[(size_t)csr_gin[j] * DINC + t];
    hbuf[(size_t)i * DINC + t] = (bf16)acc;
}

// LayerNorm over 512 features (fp32 in, fp32 out)
__global__ __launch_bounds__(256) void layernorm512(
    const float* __restrict__ cbuf, const float* __restrict__ g,
    const float* __restrict__ b, float* __restrict__ out)
{
    const int r = blockIdx.x;
    const int t = threadIdx.x;
    float2 v = *(const float2*)&cbuf[(size_t)r * HIDC + t * 2];
    float s = v.x + v.y;
    float q = v.x * v.x + v.y * v.y;
    for (int o = 1; o < 64; o <<= 1) {
        s += __shfl_xor(s, o);
        q += __shfl_xor(q, o);
    }
    __shared__ float ls[4], lq[4];
    int w = t >> 6;
    if ((t & 63) == 0) { ls[w] = s; lq[w] = q; }
    __syncthreads();
    s = ls[0] + ls[1] + ls[2] + ls[3];
    q = lq[0] + lq[1] + lq[2] + lq[3];
    float mu  = s * (1.0f / 512.0f);
    float var = q * (1.0f / 512.0f) - mu * mu;
    float rs  = rsqrtf(var + 1e-5f);
    int c0 = t * 2;
    out[(size_t)r * HIDC + c0]     = (v.x - mu) * rs * g[c0]     + b[c0];
    out[(size_t)r * HIDC + c0 + 1] = (v.y - mu) * rs * g[c0 + 1] + b[c0 + 1];
}

// ---------------------------------------------------------------------------
extern "C" void kernel_launch(void* const* d_in, const int* in_sizes, int n_in,
                              void* d_out, int out_size, void* d_ws, size_t ws_size,
                              hipStream_t stream)
{
    const float* x      = (const float*)d_in[0];
    const float* W_l    = (const float*)d_in[1];
    const float* W_r    = (const float*)d_in[2];
    const float* att    = (const float*)d_in[3];
    const float* b_gat  = (const float*)d_in[4];
    const float* gin_W1 = (const float*)d_in[5];
    const float* gin_b1 = (const float*)d_in[6];
    const float* gin_W2 = (const float*)d_in[7];
    const float* gin_b2 = (const float*)d_in[8];
    const float* fus_W  = (const float*)d_in[9];
    const float* fus_b  = (const float*)d_in[10];
    const float* ln_g   = (const float*)d_in[11];
    const float* ln_b   = (const float*)d_in[12];
    const int*   eidx   = (const int*)d_in[13];

    const int E = in_sizes[13] / 2;
    const int N = in_sizes[0] / DINC;  // 8192
    const int* src = eidx;
    const int* dst = eidx + E;

    char* ws = (char*)d_ws;
    size_t off = 0;
    auto alloc = [&](size_t bytes) -> void* {
        void* p = ws + off;
        off = (off + bytes + 255) & ~(size_t)255;
        return p;
    };
    bf16* xb     = (bf16*)alloc((size_t)N * DINC * 2);
    bf16* xlr    = (bf16*)alloc((size_t)N * HIDC * 2);
    bf16* Wlr_t  = (bf16*)alloc((size_t)512 * 256 * 2);
    bf16* W1t    = (bf16*)alloc((size_t)256 * 256 * 2);
    bf16* W2t    = (bf16*)alloc((size_t)256 * 256 * 2);
    bf16* Wft    = (bf16*)alloc((size_t)512 * 512 * 2);
    bf16* hbuf   = (bf16*)alloc((size_t)N * DINC * 2);
    bf16* gin1   = (bf16*)alloc((size_t)N * DINC * 2);
    bf16* cat    = (bf16*)alloc((size_t)N * HIDC * 2);
    float* cbuf  = (float*)alloc((size_t)N * HIDC * 4);
    int* cnt_dst = (int*)alloc((size_t)N * 4);
    int* cnt_src = (int*)alloc((size_t)N * 4);
    int* off_dst = (int*)alloc((size_t)(N + 1) * 4);
    int* cur_dst = (int*)alloc((size_t)N * 4);
    int* off_src = (int*)alloc((size_t)(N + 1) * 4);
    int* cur_src = (int*)alloc((size_t)N * 4);
    int* csr_src = (int*)alloc((size_t)E * 4);
    int* csr_gin = (int*)alloc((size_t)E * 4);
    unsigned char* flags  = (unsigned char*)alloc((size_t)E);
    unsigned int*  bitmap = (unsigned int*)alloc((size_t)N * (size_t)N / 8);

    hipMemsetAsync(cnt_dst, 0, (size_t)N * 8, stream);
    hipMemsetAsync(bitmap, 0, (size_t)N * (size_t)N / 8, stream);

    transpose_w<<<dim3(16, 16, 5), 256, 0, stream>>>(W_l, W_r, gin_W1, gin_W2, fus_W,
                                                     Wlr_t, W1t, W2t, Wft);
    convert_x<<<1024, 256, 0, stream>>>(x, xb);

    build_hist<<<(E + 255) / 256, 256, 0, stream>>>(src, dst, E, N, cnt_dst, cnt_src, bitmap, flags);
    scan_both<<<2, 1024, 0, stream>>>(cnt_dst, off_dst, cur_dst, cnt_src, off_src, cur_src);
    scatter_edges<<<(E + 255) / 256, 256, 0, stream>>>(src, dst, E, cur_dst, cur_src, flags, csr_src, csr_gin);

    // xlr = x @ [W_l | W_r]  (bf16 MFMA)
    gemm64<0, 1><<<dim3(8, 128), 256, 0, stream>>>(xb, Wlr_t, nullptr, xlr, 256, HIDC, 0);

    gin_aggregate<<<N, 256, 0, stream>>>(xb, csr_gin, off_src, hbuf);
    gat_fused<<<N, 256, 0, stream>>>(xlr, csr_src, off_dst, att, b_gat, cat);

    gemm64<1, 1><<<dim3(4, 128), 256, 0, stream>>>(hbuf, W1t, gin_b1, gin1, 256, DINC, 0);
    gemm64<0, 1><<<dim3(4, 128), 256, 0, stream>>>(gin1, W2t, gin_b2, cat, 256, HIDC, 256);

    gemm64<1, 0><<<dim3(8, 128), 256, 0, stream>>>(cat, Wft, fus_b, cbuf, 512, HIDC, 0);
    layernorm512<<<N, 256, 0, stream>>>(cbuf, ln_g, ln_b, (float*)d_out);

    (void)n_in; (void)out_size; (void)ws_size;
}

// Round 5
// 188.089 us; speedup vs baseline: 2.5803x; 1.0415x over previous
//
#include <hip/hip_runtime.h>

typedef __bf16 bf16;
typedef __attribute__((ext_vector_type(8))) __bf16 bf16x8;
typedef __attribute__((ext_vector_type(4))) float f32x4;

#define DINC 256
#define HIDC 512
#define CAP  48    // fast-path max (deg+1): rows cached in LDS
#define MAXE 512   // mid-path max (deg+1): scores in LDS, global gather

__device__ __forceinline__ float lrelu02(float v) { return fmaxf(v, 0.2f * v); }

__device__ __forceinline__ void gload_lds16(const void* g, void* l) {
    __builtin_amdgcn_global_load_lds(
        (const __attribute__((address_space(1))) unsigned int*)g,
        (__attribute__((address_space(3))) unsigned int*)l, 16, 0, 0);
}

// ---------------------------------------------------------------------------
// Zero-fill cnt arrays + dedupe bitmap in one launch (replaces rocclr fills).
// ---------------------------------------------------------------------------
typedef __attribute__((ext_vector_type(4))) unsigned int u32x4;
__global__ __launch_bounds__(256) void fill_zero(
    u32x4* __restrict__ cnt, int cnt4, u32x4* __restrict__ bm, int bm4)
{
    const int stride = gridDim.x * 256;
    const int gid = blockIdx.x * 256 + threadIdx.x;
    const u32x4 z = {0u, 0u, 0u, 0u};
    for (int i = gid; i < cnt4; i += stride) cnt[i] = z;
    for (int i = gid; i < bm4; i += stride) bm[i] = z;
}

// ---------------------------------------------------------------------------
// bf16 MFMA GEMM, 64x64 tile, BK=64. 256 thr = 4 waves, wave = 32x32 quadrant.
// A: [M][K] bf16 row-major. Bt: [N][K] bf16 (pre-transposed weights).
// ---------------------------------------------------------------------------
template<int RELU, int OUTBF16>
__global__ __launch_bounds__(256) void gemm64(
    const bf16* __restrict__ A, const bf16* __restrict__ Bt,
    const float* __restrict__ bias, void* __restrict__ Cout,
    int K, int ldc, int col_off)
{
    __shared__ bf16 As[64 * 64];
    __shared__ bf16 Bs[64 * 64];
    const int t = threadIdx.x;
    const int w = t >> 6, lane = t & 63;
    const long brow = (long)blockIdx.y * 64;
    const long bcol = (long)blockIdx.x * 64;
    const int wr = (w >> 1) * 32, wc = (w & 1) * 32;
    const int fr = lane & 15, half = lane >> 4;
    const int srow = t >> 3;            // staging row (first 32-row half)
    const int scol = (t & 7) * 8;       // staging k-offset (elements)

    const bf16* Ag = A  + (brow + srow) * K + scol;
    const bf16* Bg = Bt + (bcol + srow) * K + scol;
    const long rowK32 = (long)32 * K;

    f32x4 acc[2][2] = {};

    for (int k0 = 0; k0 < K; k0 += 64) {
        __syncthreads();
        gload_lds16(Ag + k0,          &As[t * 8]);
        gload_lds16(Ag + k0 + rowK32, &As[2048 + t * 8]);
        gload_lds16(Bg + k0,          &Bs[t * 8]);
        gload_lds16(Bg + k0 + rowK32, &Bs[2048 + t * 8]);
        __syncthreads();
#pragma unroll
        for (int ks = 0; ks < 2; ++ks) {
            bf16x8 af[2], bfr[2];
#pragma unroll
            for (int i = 0; i < 2; ++i)
                af[i] = *(const bf16x8*)&As[(wr + i * 16 + fr) * 64 + ks * 32 + half * 8];
#pragma unroll
            for (int j = 0; j < 2; ++j)
                bfr[j] = *(const bf16x8*)&Bs[(wc + j * 16 + fr) * 64 + ks * 32 + half * 8];
#pragma unroll
            for (int i = 0; i < 2; ++i)
#pragma unroll
                for (int j = 0; j < 2; ++j)
                    acc[i][j] = __builtin_amdgcn_mfma_f32_16x16x32_bf16(
                        af[i], bfr[j], acc[i][j], 0, 0, 0);
        }
    }

#pragma unroll
    for (int i = 0; i < 2; ++i) {
#pragma unroll
        for (int j = 0; j < 2; ++j) {
            const long gcol = bcol + wc + j * 16 + fr;
            const float bv = bias ? bias[gcol] : 0.0f;
#pragma unroll
            for (int v = 0; v < 4; ++v) {
                const long grow = brow + wr + i * 16 + half * 4 + v;
                float val = acc[i][j][v] + bv;
                if (RELU) val = fmaxf(val, 0.0f);
                if (OUTBF16) ((bf16*)Cout)[grow * ldc + col_off + gcol] = (bf16)val;
                else         ((float*)Cout)[grow * ldc + col_off + gcol] = val;
            }
        }
    }
}

// ---------------------------------------------------------------------------
// prep: z=0..4 coalesced weight transpose+convert (32x32 LDS tile);
//       z=5 converts x to bf16 (grid-stride).
// ---------------------------------------------------------------------------
__global__ __launch_bounds__(256) void prep(
    const float* __restrict__ W_l, const float* __restrict__ W_r,
    const float* __restrict__ gin_W1, const float* __restrict__ gin_W2,
    const float* __restrict__ fus_W, const float* __restrict__ x,
    bf16* __restrict__ Wlr_t, bf16* __restrict__ W1t, bf16* __restrict__ W2t,
    bf16* __restrict__ Wft, bf16* __restrict__ xb)
{
    const int z = blockIdx.z;
    if (z == 5) {
        // 8192*256 f32 -> bf16, 256 blocks x 256 thr x 4 chunks x 8 elems
        const int u0 = (blockIdx.y * 16 + blockIdx.x) * 256 + threadIdx.x;
        const float4* xv = (const float4*)x;
#pragma unroll
        for (int r = 0; r < 4; ++r) {
            const int u = u0 + r * 65536;
            float4 a = xv[(size_t)u * 2], b = xv[(size_t)u * 2 + 1];
            bf16x8 o;
            o[0] = (bf16)a.x; o[1] = (bf16)a.y; o[2] = (bf16)a.z; o[3] = (bf16)a.w;
            o[4] = (bf16)b.x; o[5] = (bf16)b.y; o[6] = (bf16)b.z; o[7] = (bf16)b.w;
            *(bf16x8*)&xb[(size_t)u * 8] = o;
        }
        return;
    }
    const float* src; bf16* dst; int K, Nc;
    switch (z) {
        case 0: src = W_l;    dst = Wlr_t;             K = 256; Nc = 256; break;
        case 1: src = W_r;    dst = Wlr_t + 256 * 256; K = 256; Nc = 256; break;
        case 2: src = gin_W1; dst = W1t;               K = 256; Nc = 256; break;
        case 3: src = gin_W2; dst = W2t;               K = 256; Nc = 256; break;
        default: src = fus_W; dst = Wft;               K = 512; Nc = 512; break;
    }
    const int bn = blockIdx.x * 32, bk = blockIdx.y * 32;
    if (bn >= Nc || bk >= K) return;
    __shared__ float tile[32][33];
    const int tx = threadIdx.x & 31, ty = threadIdx.x >> 5;
#pragma unroll
    for (int r = 0; r < 32; r += 8)
        tile[ty + r][tx] = src[(size_t)(bk + ty + r) * Nc + bn + tx];
    __syncthreads();
#pragma unroll
    for (int r = 0; r < 32; r += 8)
        dst[(size_t)(bn + ty + r) * K + bk + tx] = (bf16)tile[tx][ty + r];
}

// ---------------------------------------------------------------------------
// CSR build
// ---------------------------------------------------------------------------
__global__ __launch_bounds__(256) void build_hist(
    const int* __restrict__ src, const int* __restrict__ dst, int E, int N,
    int* __restrict__ cnt_dst, int* __restrict__ cnt_src,
    unsigned int* __restrict__ bitmap, unsigned char* __restrict__ flags)
{
    int e = blockIdx.x * 256 + threadIdx.x;
    if (e >= E) return;
    int s = src[e], d = dst[e];
    atomicAdd(&cnt_dst[d], 1);
    unsigned int key  = (unsigned int)s * (unsigned int)N + (unsigned int)d;
    unsigned int word = key >> 5;
    unsigned int bit  = 1u << (key & 31u);
    unsigned int old  = atomicOr(&bitmap[word], bit);
    int own = (old & bit) == 0u;
    flags[e] = (unsigned char)own;
    if (own) atomicAdd(&cnt_src[s], 1);
}

__global__ __launch_bounds__(1024) void scan_both(
    const int* __restrict__ cnt_dst, int* __restrict__ off_dst, int* __restrict__ cur_dst,
    const int* __restrict__ cnt_src, int* __restrict__ off_src, int* __restrict__ cur_src)
{
    const int* cnt = blockIdx.x ? cnt_src : cnt_dst;
    int* off = blockIdx.x ? off_src : off_dst;
    int* cur = blockIdx.x ? cur_src : cur_dst;
    __shared__ int lds[1024];
    const int t = threadIdx.x;
    const int base = t * 8;
    int v[8]; int s = 0;
#pragma unroll
    for (int j = 0; j < 8; ++j) { v[j] = cnt[base + j]; s += v[j]; }
    lds[t] = s;
    __syncthreads();
    int mine = s;
    for (int o = 1; o < 1024; o <<= 1) {
        int add = (t >= o) ? lds[t - o] : 0;
        __syncthreads();
        lds[t] += add;
        __syncthreads();
    }
    int run = lds[t] - mine;
#pragma unroll
    for (int j = 0; j < 8; ++j) { off[base + j] = run; cur[base + j] = run; run += v[j]; }
    if (t == 1023) off[8192] = run;
}

__global__ __launch_bounds__(256) void scatter_edges(
    const int* __restrict__ src, const int* __restrict__ dst, int E,
    int* __restrict__ cur_dst, int* __restrict__ cur_src,
    const unsigned char* __restrict__ flags,
    int* __restrict__ csr_src, int* __restrict__ csr_gin)
{
    int e = blockIdx.x * 256 + threadIdx.x;
    if (e >= E) return;
    int s = src[e], d = dst[e];
    int p = atomicAdd(&cur_dst[d], 1);
    csr_src[p] = s;
    if (flags[e]) {
        int q = atomicAdd(&cur_src[s], 1);
        csr_gin[q] = d;
    }
}

// ---------------------------------------------------------------------------
// Fused GATv2 v3 (3-tier): fast path caches rows in LDS; mid path caches
// scores only; serial fallback for huge degree.
// ---------------------------------------------------------------------------
__global__ __launch_bounds__(256) void gat_fused(
    const bf16* __restrict__ xlr, const int* __restrict__ csr_src,
    const int* __restrict__ off_dst, const float* __restrict__ att,
    const float* __restrict__ b_gat, bf16* __restrict__ cat)
{
    __shared__ __align__(16) char lds_raw[CAP * 512];   // rows[CAP][256]bf16 / ssc[4][MAXE]f32
    __shared__ float sc[4 * CAP];
    __shared__ float sden[4];
    bf16* rows = (bf16*)lds_raw;
    float* ssc = (float*)lds_raw;

    const int d = blockIdx.x, t = threadIdx.x;
    const int beg = off_dst[d];
    const int deg = off_dst[d + 1] - beg;
    const int cnt = deg + 1;

    if (cnt <= CAP) {
        const int e8 = t >> 5, g = t & 31, h8 = g >> 3;
        float xr8[8], at8[8];
        {
            bf16x8 xv = *(const bf16x8*)&xlr[(size_t)d * HIDC + 256 + g * 8];
#pragma unroll
            for (int f = 0; f < 8; ++f) xr8[f] = (float)xv[f];
            float4 a0 = *(const float4*)&att[g * 8];
            float4 a1 = *(const float4*)&att[g * 8 + 4];
            at8[0] = a0.x; at8[1] = a0.y; at8[2] = a0.z; at8[3] = a0.w;
            at8[4] = a1.x; at8[5] = a1.y; at8[6] = a1.z; at8[7] = a1.w;
        }
        for (int base = 0; base < cnt; base += 8) {
            const int jj = base + e8;
            int s = d;
            if (jj < deg) s = csr_src[beg + jj];
            bf16x8 xv = *(const bf16x8*)&xlr[(size_t)s * HIDC + g * 8];
            float p = 0.0f;
#pragma unroll
            for (int f = 0; f < 8; ++f)
                p += lrelu02((float)xv[f] + xr8[f]) * at8[f];
            p += __shfl_xor(p, 1);
            p += __shfl_xor(p, 2);
            p += __shfl_xor(p, 4);
            if (jj < cnt) {
                *(bf16x8*)&rows[jj * 256 + g * 8] = xv;
                if ((g & 7) == 0) sc[h8 * CAP + jj] = p;
            }
        }
        __syncthreads();
        {
            const int h = t >> 6, k = t & 63;
            float m = (k < cnt) ? sc[h * CAP + k] : -1e30f;
#pragma unroll
            for (int o = 1; o < 64; o <<= 1) m = fmaxf(m, __shfl_xor(m, o));
            float ds = 0.0f;
            if (k < cnt) {
                ds = __expf(sc[h * CAP + k] - m);
                sc[h * CAP + k] = ds;
            }
#pragma unroll
            for (int o = 1; o < 64; o <<= 1) ds += __shfl_xor(ds, o);
            if (k == 0) sden[h] = ds;
        }
        __syncthreads();
        const int h = t >> 6;
        const float* wrow = &sc[h * CAP];
        float acc = 0.0f;
#pragma unroll 4
        for (int jj = 0; jj < cnt; ++jj)
            acc = fmaf(wrow[jj], (float)rows[jj * 256 + t], acc);
        cat[(size_t)d * HIDC + t] = (bf16)(acc / sden[h] + b_gat[t]);
        return;
    }

    if (cnt <= MAXE) {
        const int e8 = t >> 5, g = t & 31, h8 = g >> 3;
        float xr8[8], at8[8];
        {
            bf16x8 xv = *(const bf16x8*)&xlr[(size_t)d * HIDC + 256 + g * 8];
#pragma unroll
            for (int f = 0; f < 8; ++f) xr8[f] = (float)xv[f];
            float4 a0 = *(const float4*)&att[g * 8];
            float4 a1 = *(const float4*)&att[g * 8 + 4];
            at8[0] = a0.x; at8[1] = a0.y; at8[2] = a0.z; at8[3] = a0.w;
            at8[4] = a1.x; at8[5] = a1.y; at8[6] = a1.z; at8[7] = a1.w;
        }
        for (int base = 0; base < cnt; base += 8) {
            const int jj = base + e8;
            int s = d;
            if (jj < deg) s = csr_src[beg + jj];
            bf16x8 xv = *(const bf16x8*)&xlr[(size_t)s * HIDC + g * 8];
            float p = 0.0f;
#pragma unroll
            for (int f = 0; f < 8; ++f)
                p += lrelu02((float)xv[f] + xr8[f]) * at8[f];
            p += __shfl_xor(p, 1);
            p += __shfl_xor(p, 2);
            p += __shfl_xor(p, 4);
            if (jj < cnt && (g & 7) == 0) ssc[h8 * MAXE + jj] = p;
        }
        __syncthreads();
        {
            const int h = t >> 6, k = t & 63;
            float m = -1e30f;
            for (int jj = k; jj < cnt; jj += 64) m = fmaxf(m, ssc[h * MAXE + jj]);
#pragma unroll
            for (int o = 1; o < 64; o <<= 1) m = fmaxf(m, __shfl_xor(m, o));
            float ds = 0.0f;
            for (int jj = k; jj < cnt; jj += 64) {
                float wgt = __expf(ssc[h * MAXE + jj] - m);
                ssc[h * MAXE + jj] = wgt;
                ds += wgt;
            }
#pragma unroll
            for (int o = 1; o < 64; o <<= 1) ds += __shfl_xor(ds, o);
            if (k == 0) sden[h] = ds;
        }
        __syncthreads();
        const int h = t >> 6;
        const float* wrow = &ssc[h * MAXE];
        float acc = 0.0f;
        int jj = 0;
        for (; jj + 4 <= cnt; jj += 4) {
            const int s0 = (jj     < deg) ? csr_src[beg + jj]     : d;
            const int s1 = (jj + 1 < deg) ? csr_src[beg + jj + 1] : d;
            const int s2 = (jj + 2 < deg) ? csr_src[beg + jj + 2] : d;
            const int s3 = (jj + 3 < deg) ? csr_src[beg + jj + 3] : d;
            const float v0 = (float)xlr[(size_t)s0 * HIDC + t];
            const float v1 = (float)xlr[(size_t)s1 * HIDC + t];
            const float v2 = (float)xlr[(size_t)s2 * HIDC + t];
            const float v3 = (float)xlr[(size_t)s3 * HIDC + t];
            acc = fmaf(wrow[jj], v0, acc);
            acc = fmaf(wrow[jj + 1], v1, acc);
            acc = fmaf(wrow[jj + 2], v2, acc);
            acc = fmaf(wrow[jj + 3], v3, acc);
        }
        for (; jj < cnt; ++jj) {
            const int s = (jj < deg) ? csr_src[beg + jj] : d;
            acc = fmaf(wrow[jj], (float)xlr[(size_t)s * HIDC + t], acc);
        }
        cat[(size_t)d * HIDC + t] = (bf16)(acc / sden[h] + b_gat[t]);
        return;
    }

    {   // serial fallback
        const float attv = att[t];
        const float xrv = (float)xlr[(size_t)d * HIDC + 256 + t];
        const float xld = (float)xlr[(size_t)d * HIDC + t];
        float p = lrelu02(xld + xrv) * attv;
#pragma unroll
        for (int o = 1; o < 64; o <<= 1) p += __shfl_xor(p, o);
        float m = p, denom = 1.0f, acc = xld;
        for (int j = beg; j < beg + deg; ++j) {
            const int s = csr_src[j];
            const float xls = (float)xlr[(size_t)s * HIDC + t];
            float q = lrelu02(xls + xrv) * attv;
#pragma unroll
            for (int o = 1; o < 64; o <<= 1) q += __shfl_xor(q, o);
            if (q > m) {
                const float r = __expf(m - q);
                denom = denom * r + 1.0f;
                acc   = acc * r + xls;
                m = q;
            } else {
                const float wgt = __expf(q - m);
                denom += wgt;
                acc   += wgt * xls;
            }
        }
        cat[(size_t)d * HIDC + t] = (bf16)(acc / denom + b_gat[t]);
    }
}

// GIN aggregation, unroll x8
__global__ __launch_bounds__(256) void gin_aggregate(
    const bf16* __restrict__ xb, const int* __restrict__ csr_gin,
    const int* __restrict__ off_src, bf16* __restrict__ hbuf)
{
    const int i = blockIdx.x, t = threadIdx.x;
    const int beg = off_src[i], end = off_src[i + 1];
    float acc = (float)xb[(size_t)i * DINC + t];
    int j = beg;
    for (; j + 8 <= end; j += 8) {
        float v[8];
#pragma unroll
        for (int u = 0; u < 8; ++u) {
            const int s = csr_gin[j + u];
            v[u] = (float)xb[(size_t)s * DINC + t];
        }
#pragma unroll
        for (int u = 0; u < 8; ++u) acc += v[u];
    }
    for (; j < end; ++j)
        acc += (float)xb[(size_t)csr_gin[j] * DINC + t];
    hbuf[(size_t)i * DINC + t] = (bf16)acc;
}

// LayerNorm over 512 features (bf16 in, fp32 out)
__global__ __launch_bounds__(256) void layernorm512(
    const bf16* __restrict__ cbuf, const float* __restrict__ g,
    const float* __restrict__ b, float* __restrict__ out)
{
    const int r = blockIdx.x;
    const int t = threadIdx.x;
    const bf16* row = &cbuf[(size_t)r * HIDC];
    float v0 = (float)row[t * 2], v1 = (float)row[t * 2 + 1];
    float s = v0 + v1;
    float q = v0 * v0 + v1 * v1;
    for (int o = 1; o < 64; o <<= 1) {
        s += __shfl_xor(s, o);
        q += __shfl_xor(q, o);
    }
    __shared__ float ls[4], lq[4];
    int w = t >> 6;
    if ((t & 63) == 0) { ls[w] = s; lq[w] = q; }
    __syncthreads();
    s = ls[0] + ls[1] + ls[2] + ls[3];
    q = lq[0] + lq[1] + lq[2] + lq[3];
    float mu  = s * (1.0f / 512.0f);
    float var = q * (1.0f / 512.0f) - mu * mu;
    float rs  = rsqrtf(var + 1e-5f);
    int c0 = t * 2;
    out[(size_t)r * HIDC + c0]     = (v0 - mu) * rs * g[c0]     + b[c0];
    out[(size_t)r * HIDC + c0 + 1] = (v1 - mu) * rs * g[c0 + 1] + b[c0 + 1];
}

// ---------------------------------------------------------------------------
extern "C" void kernel_launch(void* const* d_in, const int* in_sizes, int n_in,
                              void* d_out, int out_size, void* d_ws, size_t ws_size,
                              hipStream_t stream)
{
    const float* x      = (const float*)d_in[0];
    const float* W_l    = (const float*)d_in[1];
    const float* W_r    = (const float*)d_in[2];
    const float* att    = (const float*)d_in[3];
    const float* b_gat  = (const float*)d_in[4];
    const float* gin_W1 = (const float*)d_in[5];
    const float* gin_b1 = (const float*)d_in[6];
    const float* gin_W2 = (const float*)d_in[7];
    const float* gin_b2 = (const float*)d_in[8];
    const float* fus_W  = (const float*)d_in[9];
    const float* fus_b  = (const float*)d_in[10];
    const float* ln_g   = (const float*)d_in[11];
    const float* ln_b   = (const float*)d_in[12];
    const int*   eidx   = (const int*)d_in[13];

    const int E = in_sizes[13] / 2;
    const int N = in_sizes[0] / DINC;  // 8192
    const int* src = eidx;
    const int* dst = eidx + E;

    char* ws = (char*)d_ws;
    size_t off = 0;
    auto alloc = [&](size_t bytes) -> void* {
        void* p = ws + off;
        off = (off + bytes + 255) & ~(size_t)255;
        return p;
    };
    bf16* xb     = (bf16*)alloc((size_t)N * DINC * 2);
    bf16* xlr    = (bf16*)alloc((size_t)N * HIDC * 2);
    bf16* Wlr_t  = (bf16*)alloc((size_t)512 * 256 * 2);
    bf16* W1t    = (bf16*)alloc((size_t)256 * 256 * 2);
    bf16* W2t    = (bf16*)alloc((size_t)256 * 256 * 2);
    bf16* Wft    = (bf16*)alloc((size_t)512 * 512 * 2);
    bf16* hbuf   = (bf16*)alloc((size_t)N * DINC * 2);
    bf16* gin1   = (bf16*)alloc((size_t)N * DINC * 2);
    bf16* cat    = (bf16*)alloc((size_t)N * HIDC * 2);
    bf16* cbuf   = (bf16*)alloc((size_t)N * HIDC * 2);
    int* cnt_dst = (int*)alloc((size_t)N * 4);          // cnt_dst+cnt_src contiguous
    int* cnt_src = (int*)alloc((size_t)N * 4);
    int* off_dst = (int*)alloc((size_t)(N + 1) * 4);
    int* cur_dst = (int*)alloc((size_t)N * 4);
    int* off_src = (int*)alloc((size_t)(N + 1) * 4);
    int* cur_src = (int*)alloc((size_t)N * 4);
    int* csr_src = (int*)alloc((size_t)E * 4);
    int* csr_gin = (int*)alloc((size_t)E * 4);
    unsigned char* flags  = (unsigned char*)alloc((size_t)E);
    unsigned int*  bitmap = (unsigned int*)alloc((size_t)N * (size_t)N / 8);

    // zero cnt arrays (contiguous 2N ints) + bitmap, one kernel
    fill_zero<<<2048, 256, 0, stream>>>(
        (u32x4*)cnt_dst, (2 * N) / 4,
        (u32x4*)bitmap, (int)((size_t)N * N / 32 / 4));

    prep<<<dim3(16, 16, 6), 256, 0, stream>>>(W_l, W_r, gin_W1, gin_W2, fus_W, x,
                                              Wlr_t, W1t, W2t, Wft, xb);

    build_hist<<<(E + 255) / 256, 256, 0, stream>>>(src, dst, E, N, cnt_dst, cnt_src, bitmap, flags);
    scan_both<<<2, 1024, 0, stream>>>(cnt_dst, off_dst, cur_dst, cnt_src, off_src, cur_src);
    scatter_edges<<<(E + 255) / 256, 256, 0, stream>>>(src, dst, E, cur_dst, cur_src, flags, csr_src, csr_gin);

    // xlr = x @ [W_l | W_r]  (bf16 MFMA)
    gemm64<0, 1><<<dim3(8, 128), 256, 0, stream>>>(xb, Wlr_t, nullptr, xlr, 256, HIDC, 0);

    gin_aggregate<<<N, 256, 0, stream>>>(xb, csr_gin, off_src, hbuf);
    gat_fused<<<N, 256, 0, stream>>>(xlr, csr_src, off_dst, att, b_gat, cat);

    gemm64<1, 1><<<dim3(4, 128), 256, 0, stream>>>(hbuf, W1t, gin_b1, gin1, 256, DINC, 0);
    gemm64<0, 1><<<dim3(4, 128), 256, 0, stream>>>(gin1, W2t, gin_b2, cat, 256, HIDC, 256);

    // fusion GEMM -> bf16 cbuf, then LayerNorm (bf16 in, f32 out)
    gemm64<1, 1><<<dim3(8, 128), 256, 0, stream>>>(cat, Wft, fus_b, cbuf, 512, HIDC, 0);
    layernorm512<<<N, 256, 0, stream>>>(cbuf, ln_g, ln_b, (float*)d_out);

    (void)n_in; (void)out_size; (void)ws_size;
}

// Round 6
// 182.051 us; speedup vs baseline: 2.6658x; 1.0332x over previous
//
#include <hip/hip_runtime.h>

typedef __bf16 bf16;
typedef __attribute__((ext_vector_type(8))) __bf16 bf16x8;
typedef __attribute__((ext_vector_type(4))) float f32x4;
typedef __attribute__((ext_vector_type(4))) unsigned int u32x4;

#define DINC 256
#define HIDC 512
#define CAP  48    // fast-path max (deg+1): rows cached in LDS
#define MAXE 512   // mid-path max (deg+1): scores in LDS, global gather

__device__ __forceinline__ float lrelu02(float v) { return fmaxf(v, 0.2f * v); }

__device__ __forceinline__ void gload_lds16(const void* g, void* l) {
    __builtin_amdgcn_global_load_lds(
        (const __attribute__((address_space(1))) unsigned int*)g,
        (__attribute__((address_space(3))) unsigned int*)l, 16, 0, 0);
}

// ---------------------------------------------------------------------------
// bf16 MFMA GEMM body, 64x64 tile, BK=64. 256 thr = 4 waves, wave = 32x32.
// A: [M][K] bf16 row-major. Bt: [N][K] bf16. Callable from merged kernels.
// ---------------------------------------------------------------------------
__device__ __forceinline__ void gemm64_body(
    const bf16* __restrict__ A, const bf16* __restrict__ Bt,
    const float* __restrict__ bias, void* __restrict__ Cout,
    int K, int ldc, int col_off, int bx, int by, int relu, int outbf16,
    bf16* As, bf16* Bs)
{
    const int t = threadIdx.x;
    const int w = t >> 6, lane = t & 63;
    const long brow = (long)by * 64;
    const long bcol = (long)bx * 64;
    const int wr = (w >> 1) * 32, wc = (w & 1) * 32;
    const int fr = lane & 15, half = lane >> 4;
    const int srow = t >> 3;
    const int scol = (t & 7) * 8;

    const bf16* Ag = A  + (brow + srow) * K + scol;
    const bf16* Bg = Bt + (bcol + srow) * K + scol;
    const long rowK32 = (long)32 * K;

    f32x4 acc[2][2] = {};

    for (int k0 = 0; k0 < K; k0 += 64) {
        __syncthreads();
        gload_lds16(Ag + k0,          &As[t * 8]);
        gload_lds16(Ag + k0 + rowK32, &As[2048 + t * 8]);
        gload_lds16(Bg + k0,          &Bs[t * 8]);
        gload_lds16(Bg + k0 + rowK32, &Bs[2048 + t * 8]);
        __syncthreads();
#pragma unroll
        for (int ks = 0; ks < 2; ++ks) {
            bf16x8 af[2], bfr[2];
#pragma unroll
            for (int i = 0; i < 2; ++i)
                af[i] = *(const bf16x8*)&As[(wr + i * 16 + fr) * 64 + ks * 32 + half * 8];
#pragma unroll
            for (int j = 0; j < 2; ++j)
                bfr[j] = *(const bf16x8*)&Bs[(wc + j * 16 + fr) * 64 + ks * 32 + half * 8];
#pragma unroll
            for (int i = 0; i < 2; ++i)
#pragma unroll
                for (int j = 0; j < 2; ++j)
                    acc[i][j] = __builtin_amdgcn_mfma_f32_16x16x32_bf16(
                        af[i], bfr[j], acc[i][j], 0, 0, 0);
        }
    }

#pragma unroll
    for (int i = 0; i < 2; ++i) {
#pragma unroll
        for (int j = 0; j < 2; ++j) {
            const long gcol = bcol + wc + j * 16 + fr;
            const float bv = bias ? bias[gcol] : 0.0f;
#pragma unroll
            for (int v = 0; v < 4; ++v) {
                const long grow = brow + wr + i * 16 + half * 4 + v;
                float val = acc[i][j][v] + bv;
                if (relu) val = fmaxf(val, 0.0f);
                if (outbf16) ((bf16*)Cout)[grow * ldc + col_off + gcol] = (bf16)val;
                else         ((float*)Cout)[grow * ldc + col_off + gcol] = val;
            }
        }
    }
}

template<int RELU, int OUTBF16>
__global__ __launch_bounds__(256) void gemm64(
    const bf16* __restrict__ A, const bf16* __restrict__ Bt,
    const float* __restrict__ bias, void* __restrict__ Cout,
    int K, int ldc, int col_off)
{
    __shared__ bf16 As[64 * 64];
    __shared__ bf16 Bs[64 * 64];
    gemm64_body(A, Bt, bias, Cout, K, ldc, col_off,
                blockIdx.x, blockIdx.y, RELU, OUTBF16, As, Bs);
}

// ---------------------------------------------------------------------------
// mega_prep, grid (16,16,8):
//  z=0..4: transpose+convert f32 [K][Nc] -> bf16 [Nc][K] (dst stride ldd)
//  z=5: W2 straight convert to bf16
//  z=6: x convert to bf16
//  z=7: zero-fills (cnt, bitmap) + bias_comb = fus_b + gin_b2 @ fus_W_bot
// ---------------------------------------------------------------------------
__global__ __launch_bounds__(256) void mega_prep(
    const float* __restrict__ W_l, const float* __restrict__ W_r,
    const float* __restrict__ gin_W1, const float* __restrict__ fus_W,
    const float* __restrict__ gin_b2, const float* __restrict__ fus_b,
    const float* __restrict__ x, const float* __restrict__ W2,
    bf16* __restrict__ Wlr_t, bf16* __restrict__ W1t,
    bf16* __restrict__ Wfused_t, bf16* __restrict__ Wfbot_t,
    bf16* __restrict__ W2b, bf16* __restrict__ xb,
    float* __restrict__ bias_comb,
    u32x4* __restrict__ cnt, int cnt4, u32x4* __restrict__ bm, int bm4)
{
    const int z = blockIdx.z;
    const int t = threadIdx.x;
    if (z < 5) {
        const float* s; bf16* d; int K, Nc, ldd;
        switch (z) {
            case 0: s = W_l;            d = Wlr_t;         K = 256; Nc = 256; ldd = 256; break;
            case 1: s = W_r;            d = Wlr_t + 65536; K = 256; Nc = 256; ldd = 256; break;
            case 2: s = gin_W1;         d = W1t;           K = 256; Nc = 256; ldd = 256; break;
            case 3: s = fus_W;          d = Wfused_t;      K = 256; Nc = 512; ldd = 512; break;
            default: s = fus_W + 256 * 512; d = Wfbot_t;   K = 256; Nc = 512; ldd = 256; break;
        }
        const int bn = blockIdx.x * 32, bk = blockIdx.y * 32;
        if (bn >= Nc || bk >= K) return;
        __shared__ float tile[32][33];
        const int tx = t & 31, ty = t >> 5;
#pragma unroll
        for (int r = 0; r < 32; r += 8)
            tile[ty + r][tx] = s[(size_t)(bk + ty + r) * Nc + bn + tx];
        __syncthreads();
#pragma unroll
        for (int r = 0; r < 32; r += 8)
            d[(size_t)(bn + ty + r) * ldd + bk + tx] = (bf16)tile[tx][ty + r];
        return;
    }
    const int bid = blockIdx.y * 16 + blockIdx.x;
    if (z == 5) {
        if (bid >= 32) return;
        const int u = bid * 256 + t;
        const float4* wv = (const float4*)W2;
        float4 a = wv[(size_t)u * 2], b = wv[(size_t)u * 2 + 1];
        bf16x8 o;
        o[0] = (bf16)a.x; o[1] = (bf16)a.y; o[2] = (bf16)a.z; o[3] = (bf16)a.w;
        o[4] = (bf16)b.x; o[5] = (bf16)b.y; o[6] = (bf16)b.z; o[7] = (bf16)b.w;
        *(bf16x8*)&W2b[(size_t)u * 8] = o;
        return;
    }
    if (z == 6) {
        const int u0 = bid * 256 + t;
        const float4* xv = (const float4*)x;
#pragma unroll
        for (int r = 0; r < 4; ++r) {
            const int u = u0 + r * 65536;
            float4 a = xv[(size_t)u * 2], b = xv[(size_t)u * 2 + 1];
            bf16x8 o;
            o[0] = (bf16)a.x; o[1] = (bf16)a.y; o[2] = (bf16)a.z; o[3] = (bf16)a.w;
            o[4] = (bf16)b.x; o[5] = (bf16)b.y; o[6] = (bf16)b.z; o[7] = (bf16)b.w;
            *(bf16x8*)&xb[(size_t)u * 8] = o;
        }
        return;
    }
    // z == 7: bias_comb + zero fills
    const int gid = bid * 256 + t;
    if (gid < 512) {
        float acc = fus_b[gid];
        for (int j = 0; j < 256; ++j)
            acc += gin_b2[j] * fus_W[(size_t)(256 + j) * 512 + gid];
        bias_comb[gid] = acc;
    }
    const int stride = 256 * 256;
    const u32x4 zv = {0u, 0u, 0u, 0u};
    for (int i = gid; i < cnt4; i += stride) cnt[i] = zv;
    for (int i = gid; i < bm4; i += stride) bm[i] = zv;
}

// ---------------------------------------------------------------------------
// CSR build
// ---------------------------------------------------------------------------
__global__ __launch_bounds__(256) void build_hist(
    const int* __restrict__ src, const int* __restrict__ dst, int E, int N,
    int* __restrict__ cnt_dst, int* __restrict__ cnt_src,
    unsigned int* __restrict__ bitmap, unsigned char* __restrict__ flags)
{
    int e = blockIdx.x * 256 + threadIdx.x;
    if (e >= E) return;
    int s = src[e], d = dst[e];
    atomicAdd(&cnt_dst[d], 1);
    unsigned int key  = (unsigned int)s * (unsigned int)N + (unsigned int)d;
    unsigned int word = key >> 5;
    unsigned int bit  = 1u << (key & 31u);
    unsigned int old  = atomicOr(&bitmap[word], bit);
    int own = (old & bit) == 0u;
    flags[e] = (unsigned char)own;
    if (own) atomicAdd(&cnt_src[s], 1);
}

__global__ __launch_bounds__(1024) void scan_both(
    const int* __restrict__ cnt_dst, int* __restrict__ off_dst, int* __restrict__ cur_dst,
    const int* __restrict__ cnt_src, int* __restrict__ off_src, int* __restrict__ cur_src)
{
    const int* cnt = blockIdx.x ? cnt_src : cnt_dst;
    int* off = blockIdx.x ? off_src : off_dst;
    int* cur = blockIdx.x ? cur_src : cur_dst;
    __shared__ int lds[1024];
    const int t = threadIdx.x;
    const int base = t * 8;
    int v[8]; int s = 0;
#pragma unroll
    for (int j = 0; j < 8; ++j) { v[j] = cnt[base + j]; s += v[j]; }
    lds[t] = s;
    __syncthreads();
    int mine = s;
    for (int o = 1; o < 1024; o <<= 1) {
        int add = (t >= o) ? lds[t - o] : 0;
        __syncthreads();
        lds[t] += add;
        __syncthreads();
    }
    int run = lds[t] - mine;
#pragma unroll
    for (int j = 0; j < 8; ++j) { off[base + j] = run; cur[base + j] = run; run += v[j]; }
    if (t == 1023) off[8192] = run;
}

// ---------------------------------------------------------------------------
// Heterogeneous launch: scatter (1024 blk) | xlr GEMM (1024 blk) | Wcomb (32)
// All three depend only on {mega_prep, scan}; no cross-block deps inside.
// ---------------------------------------------------------------------------
__global__ __launch_bounds__(256) void scatter_gemms(
    const int* __restrict__ src, const int* __restrict__ dst, int E,
    int* __restrict__ cur_dst, int* __restrict__ cur_src,
    const unsigned char* __restrict__ flags,
    int* __restrict__ csr_src, int* __restrict__ csr_gin,
    const bf16* __restrict__ xb, const bf16* __restrict__ Wlr_t,
    bf16* __restrict__ xlr,
    const bf16* __restrict__ Wfbot_t, const bf16* __restrict__ W2b,
    bf16* __restrict__ Wfused_t)
{
    __shared__ bf16 As[64 * 64];
    __shared__ bf16 Bs[64 * 64];
    const int nsc = (E + 255) >> 8;
    int bid = blockIdx.x;
    if (bid < nsc) {
        int e = bid * 256 + threadIdx.x;
        if (e >= E) return;
        int s = src[e], d = dst[e];
        int p = atomicAdd(&cur_dst[d], 1);
        csr_src[p] = s;
        if (flags[e]) {
            int q = atomicAdd(&cur_src[s], 1);
            csr_gin[q] = d;
        }
        return;
    }
    bid -= nsc;
    if (bid < 1024) {
        // xlr = xb @ [W_l|W_r] : M=8192, N=512, K=256
        gemm64_body(xb, Wlr_t, nullptr, xlr, 256, HIDC, 0,
                    bid & 7, bid >> 3, 0, 1, As, Bs);
        return;
    }
    bid -= 1024;
    // Wfused bottom: Wcomb^T placement. M=512 (n), N=256 (k), K=256 (j).
    gemm64_body(Wfbot_t, W2b, nullptr, Wfused_t, 256, HIDC, 256,
                bid & 3, bid >> 2, 0, 1, As, Bs);
}

// ---------------------------------------------------------------------------
// Merged GAT (blocks 0..N-1) + GIN aggregate (blocks N..2N-1).
// ---------------------------------------------------------------------------
__global__ __launch_bounds__(256) void gatgin(
    const bf16* __restrict__ xlr, const int* __restrict__ csr_src,
    const int* __restrict__ off_dst, const float* __restrict__ att,
    const float* __restrict__ b_gat, bf16* __restrict__ cat,
    const bf16* __restrict__ xb, const int* __restrict__ csr_gin,
    const int* __restrict__ off_src, bf16* __restrict__ hbuf, int N)
{
    __shared__ __align__(16) char lds_raw[CAP * 512];
    __shared__ float sc[4 * CAP];
    __shared__ float sden[4];
    const int t = threadIdx.x;

    if (blockIdx.x >= N) {
        // ---------------- GIN aggregate ----------------
        const int i = blockIdx.x - N;
        const int beg = off_src[i], end = off_src[i + 1];
        float acc = (float)xb[(size_t)i * DINC + t];
        int j = beg;
        for (; j + 8 <= end; j += 8) {
            float v[8];
#pragma unroll
            for (int u = 0; u < 8; ++u)
                v[u] = (float)xb[(size_t)csr_gin[j + u] * DINC + t];
#pragma unroll
            for (int u = 0; u < 8; ++u) acc += v[u];
        }
        for (; j < end; ++j)
            acc += (float)xb[(size_t)csr_gin[j] * DINC + t];
        hbuf[(size_t)i * DINC + t] = (bf16)acc;
        return;
    }

    // ---------------- GATv2 ----------------
    bf16* rows = (bf16*)lds_raw;
    float* ssc = (float*)lds_raw;
    const int d = blockIdx.x;
    const int beg = off_dst[d];
    const int deg = off_dst[d + 1] - beg;
    const int cnt = deg + 1;

    if (cnt <= CAP) {
        const int e8 = t >> 5, g = t & 31, h8 = g >> 3;
        float xr8[8], at8[8];
        {
            bf16x8 xv = *(const bf16x8*)&xlr[(size_t)d * HIDC + 256 + g * 8];
#pragma unroll
            for (int f = 0; f < 8; ++f) xr8[f] = (float)xv[f];
            float4 a0 = *(const float4*)&att[g * 8];
            float4 a1 = *(const float4*)&att[g * 8 + 4];
            at8[0] = a0.x; at8[1] = a0.y; at8[2] = a0.z; at8[3] = a0.w;
            at8[4] = a1.x; at8[5] = a1.y; at8[6] = a1.z; at8[7] = a1.w;
        }
        // 16 rows in flight per iteration (2 slots of 8)
        for (int base = 0; base < cnt; base += 16) {
            const int j0 = base + e8, j1 = base + 8 + e8;
            const int s0 = (j0 < deg) ? csr_src[beg + j0] : d;
            const int s1 = (j1 < deg) ? csr_src[beg + j1] : d;
            bf16x8 v0 = *(const bf16x8*)&xlr[(size_t)s0 * HIDC + g * 8];
            bf16x8 v1 = *(const bf16x8*)&xlr[(size_t)s1 * HIDC + g * 8];
            float p0 = 0.0f, p1 = 0.0f;
#pragma unroll
            for (int f = 0; f < 8; ++f) {
                p0 += lrelu02((float)v0[f] + xr8[f]) * at8[f];
                p1 += lrelu02((float)v1[f] + xr8[f]) * at8[f];
            }
            p0 += __shfl_xor(p0, 1); p1 += __shfl_xor(p1, 1);
            p0 += __shfl_xor(p0, 2); p1 += __shfl_xor(p1, 2);
            p0 += __shfl_xor(p0, 4); p1 += __shfl_xor(p1, 4);
            if (j0 < cnt) {
                *(bf16x8*)&rows[j0 * 256 + g * 8] = v0;
                if ((g & 7) == 0) sc[h8 * CAP + j0] = p0;
            }
            if (j1 < cnt) {
                *(bf16x8*)&rows[j1 * 256 + g * 8] = v1;
                if ((g & 7) == 0) sc[h8 * CAP + j1] = p1;
            }
        }
        __syncthreads();
        {
            const int h = t >> 6, k = t & 63;
            float m = (k < cnt) ? sc[h * CAP + k] : -1e30f;
#pragma unroll
            for (int o = 1; o < 64; o <<= 1) m = fmaxf(m, __shfl_xor(m, o));
            float ds = 0.0f;
            if (k < cnt) {
                ds = __expf(sc[h * CAP + k] - m);
                sc[h * CAP + k] = ds;
            }
#pragma unroll
            for (int o = 1; o < 64; o <<= 1) ds += __shfl_xor(ds, o);
            if (k == 0) sden[h] = ds;
        }
        __syncthreads();
        const int h = t >> 6;
        const float* wrow = &sc[h * CAP];
        float acc = 0.0f;
#pragma unroll 4
        for (int jj = 0; jj < cnt; ++jj)
            acc = fmaf(wrow[jj], (float)rows[jj * 256 + t], acc);
        cat[(size_t)d * HIDC + t] = (bf16)(acc / sden[h] + b_gat[t]);
        return;
    }

    if (cnt <= MAXE) {
        const int e8 = t >> 5, g = t & 31, h8 = g >> 3;
        float xr8[8], at8[8];
        {
            bf16x8 xv = *(const bf16x8*)&xlr[(size_t)d * HIDC + 256 + g * 8];
#pragma unroll
            for (int f = 0; f < 8; ++f) xr8[f] = (float)xv[f];
            float4 a0 = *(const float4*)&att[g * 8];
            float4 a1 = *(const float4*)&att[g * 8 + 4];
            at8[0] = a0.x; at8[1] = a0.y; at8[2] = a0.z; at8[3] = a0.w;
            at8[4] = a1.x; at8[5] = a1.y; at8[6] = a1.z; at8[7] = a1.w;
        }
        for (int base = 0; base < cnt; base += 8) {
            const int jj = base + e8;
            int s = d;
            if (jj < deg) s = csr_src[beg + jj];
            bf16x8 xv = *(const bf16x8*)&xlr[(size_t)s * HIDC + g * 8];
            float p = 0.0f;
#pragma unroll
            for (int f = 0; f < 8; ++f)
                p += lrelu02((float)xv[f] + xr8[f]) * at8[f];
            p += __shfl_xor(p, 1);
            p += __shfl_xor(p, 2);
            p += __shfl_xor(p, 4);
            if (jj < cnt && (g & 7) == 0) ssc[h8 * MAXE + jj] = p;
        }
        __syncthreads();
        {
            const int h = t >> 6, k = t & 63;
            float m = -1e30f;
            for (int jj = k; jj < cnt; jj += 64) m = fmaxf(m, ssc[h * MAXE + jj]);
#pragma unroll
            for (int o = 1; o < 64; o <<= 1) m = fmaxf(m, __shfl_xor(m, o));
            float ds = 0.0f;
            for (int jj = k; jj < cnt; jj += 64) {
                float wgt = __expf(ssc[h * MAXE + jj] - m);
                ssc[h * MAXE + jj] = wgt;
                ds += wgt;
            }
#pragma unroll
            for (int o = 1; o < 64; o <<= 1) ds += __shfl_xor(ds, o);
            if (k == 0) sden[h] = ds;
        }
        __syncthreads();
        const int h = t >> 6;
        const float* wrow = &ssc[h * MAXE];
        float acc = 0.0f;
        int jj = 0;
        for (; jj + 4 <= cnt; jj += 4) {
            const int s0 = (jj     < deg) ? csr_src[beg + jj]     : d;
            const int s1 = (jj + 1 < deg) ? csr_src[beg + jj + 1] : d;
            const int s2 = (jj + 2 < deg) ? csr_src[beg + jj + 2] : d;
            const int s3 = (jj + 3 < deg) ? csr_src[beg + jj + 3] : d;
            const float v0 = (float)xlr[(size_t)s0 * HIDC + t];
            const float v1 = (float)xlr[(size_t)s1 * HIDC + t];
            const float v2 = (float)xlr[(size_t)s2 * HIDC + t];
            const float v3 = (float)xlr[(size_t)s3 * HIDC + t];
            acc = fmaf(wrow[jj], v0, acc);
            acc = fmaf(wrow[jj + 1], v1, acc);
            acc = fmaf(wrow[jj + 2], v2, acc);
            acc = fmaf(wrow[jj + 3], v3, acc);
        }
        for (; jj < cnt; ++jj) {
            const int s = (jj < deg) ? csr_src[beg + jj] : d;
            acc = fmaf(wrow[jj], (float)xlr[(size_t)s * HIDC + t], acc);
        }
        cat[(size_t)d * HIDC + t] = (bf16)(acc / sden[h] + b_gat[t]);
        return;
    }

    {   // serial fallback
        const float attv = att[t];
        const float xrv = (float)xlr[(size_t)d * HIDC + 256 + t];
        const float xld = (float)xlr[(size_t)d * HIDC + t];
        float p = lrelu02(xld + xrv) * attv;
#pragma unroll
        for (int o = 1; o < 64; o <<= 1) p += __shfl_xor(p, o);
        float m = p, denom = 1.0f, acc = xld;
        for (int j = beg; j < beg + deg; ++j) {
            const int s = csr_src[j];
            const float xls = (float)xlr[(size_t)s * HIDC + t];
            float q = lrelu02(xls + xrv) * attv;
#pragma unroll
            for (int o = 1; o < 64; o <<= 1) q += __shfl_xor(q, o);
            if (q > m) {
                const float r = __expf(m - q);
                denom = denom * r + 1.0f;
                acc   = acc * r + xls;
                m = q;
            } else {
                const float wgt = __expf(q - m);
                denom += wgt;
                acc   += wgt * xls;
            }
        }
        cat[(size_t)d * HIDC + t] = (bf16)(acc / denom + b_gat[t]);
    }
}

// LayerNorm over 512 features (bf16 in, fp32 out)
__global__ __launch_bounds__(256) void layernorm512(
    const bf16* __restrict__ cbuf, const float* __restrict__ g,
    const float* __restrict__ b, float* __restrict__ out)
{
    const int r = blockIdx.x;
    const int t = threadIdx.x;
    const bf16* row = &cbuf[(size_t)r * HIDC];
    float v0 = (float)row[t * 2], v1 = (float)row[t * 2 + 1];
    float s = v0 + v1;
    float q = v0 * v0 + v1 * v1;
    for (int o = 1; o < 64; o <<= 1) {
        s += __shfl_xor(s, o);
        q += __shfl_xor(q, o);
    }
    __shared__ float ls[4], lq[4];
    int w = t >> 6;
    if ((t & 63) == 0) { ls[w] = s; lq[w] = q; }
    __syncthreads();
    s = ls[0] + ls[1] + ls[2] + ls[3];
    q = lq[0] + lq[1] + lq[2] + lq[3];
    float mu  = s * (1.0f / 512.0f);
    float var = q * (1.0f / 512.0f) - mu * mu;
    float rs  = rsqrtf(var + 1e-5f);
    int c0 = t * 2;
    out[(size_t)r * HIDC + c0]     = (v0 - mu) * rs * g[c0]     + b[c0];
    out[(size_t)r * HIDC + c0 + 1] = (v1 - mu) * rs * g[c0 + 1] + b[c0 + 1];
}

// ---------------------------------------------------------------------------
extern "C" void kernel_launch(void* const* d_in, const int* in_sizes, int n_in,
                              void* d_out, int out_size, void* d_ws, size_t ws_size,
                              hipStream_t stream)
{
    const float* x      = (const float*)d_in[0];
    const float* W_l    = (const float*)d_in[1];
    const float* W_r    = (const float*)d_in[2];
    const float* att    = (const float*)d_in[3];
    const float* b_gat  = (const float*)d_in[4];
    const float* gin_W1 = (const float*)d_in[5];
    const float* gin_b1 = (const float*)d_in[6];
    const float* gin_W2 = (const float*)d_in[7];
    const float* gin_b2 = (const float*)d_in[8];
    const float* fus_W  = (const float*)d_in[9];
    const float* fus_b  = (const float*)d_in[10];
    const float* ln_g   = (const float*)d_in[11];
    const float* ln_b   = (const float*)d_in[12];
    const int*   eidx   = (const int*)d_in[13];

    const int E = in_sizes[13] / 2;
    const int N = in_sizes[0] / DINC;  // 8192
    const int* src = eidx;
    const int* dst = eidx + E;

    char* ws = (char*)d_ws;
    size_t off = 0;
    auto alloc = [&](size_t bytes) -> void* {
        void* p = ws + off;
        off = (off + bytes + 255) & ~(size_t)255;
        return p;
    };
    bf16* xb       = (bf16*)alloc((size_t)N * DINC * 2);
    bf16* xlr      = (bf16*)alloc((size_t)N * HIDC * 2);
    bf16* Wlr_t    = (bf16*)alloc((size_t)512 * 256 * 2);
    bf16* W1t      = (bf16*)alloc((size_t)256 * 256 * 2);
    bf16* Wfused_t = (bf16*)alloc((size_t)512 * 512 * 2);
    bf16* Wfbot_t  = (bf16*)alloc((size_t)512 * 256 * 2);
    bf16* W2b      = (bf16*)alloc((size_t)256 * 256 * 2);
    bf16* hbuf     = (bf16*)alloc((size_t)N * DINC * 2);
    bf16* cat      = (bf16*)alloc((size_t)N * HIDC * 2);
    bf16* cbuf     = (bf16*)alloc((size_t)N * HIDC * 2);
    float* bias_comb = (float*)alloc(512 * 4);
    int* cnt_dst = (int*)alloc((size_t)N * 4);   // cnt_dst+cnt_src contiguous
    int* cnt_src = (int*)alloc((size_t)N * 4);
    int* off_dst = (int*)alloc((size_t)(N + 1) * 4);
    int* cur_dst = (int*)alloc((size_t)N * 4);
    int* off_src = (int*)alloc((size_t)(N + 1) * 4);
    int* cur_src = (int*)alloc((size_t)N * 4);
    int* csr_src = (int*)alloc((size_t)E * 4);
    int* csr_gin = (int*)alloc((size_t)E * 4);
    unsigned char* flags  = (unsigned char*)alloc((size_t)E);
    unsigned int*  bitmap = (unsigned int*)alloc((size_t)N * (size_t)N / 8);

    // 1. all weight prep + x convert + fills + bias_comb
    mega_prep<<<dim3(16, 16, 8), 256, 0, stream>>>(
        W_l, W_r, gin_W1, fus_W, gin_b2, fus_b, x, gin_W2,
        Wlr_t, W1t, Wfused_t, Wfbot_t, W2b, xb, bias_comb,
        (u32x4*)cnt_dst, (2 * N) / 4,
        (u32x4*)bitmap, (int)((size_t)N * N / 32 / 4));

    // 2-3. CSR histogram + scans
    build_hist<<<(E + 255) / 256, 256, 0, stream>>>(src, dst, E, N, cnt_dst, cnt_src, bitmap, flags);
    scan_both<<<2, 1024, 0, stream>>>(cnt_dst, off_dst, cur_dst, cnt_src, off_src, cur_src);

    // 4. scatter | xlr GEMM | Wcomb GEMM (heterogeneous)
    const int nsc = (E + 255) / 256;
    scatter_gemms<<<nsc + 1024 + 32, 256, 0, stream>>>(
        src, dst, E, cur_dst, cur_src, flags, csr_src, csr_gin,
        xb, Wlr_t, xlr, Wfbot_t, W2b, Wfused_t);

    // 5. GAT + GIN aggregate (merged)
    gatgin<<<2 * N, 256, 0, stream>>>(xlr, csr_src, off_dst, att, b_gat, cat,
                                      xb, csr_gin, off_src, hbuf, N);

    // 6. gin1 = relu(hbuf @ W1 + b1) -> cat[:, 256:512]
    gemm64<1, 1><<<dim3(4, 128), 256, 0, stream>>>(hbuf, W1t, gin_b1, cat, 256, HIDC, 256);

    // 7. c = relu(cat @ Wfused + bias_comb) -> cbuf (bf16)
    gemm64<1, 1><<<dim3(8, 128), 256, 0, stream>>>(cat, Wfused_t, bias_comb, cbuf, 512, HIDC, 0);

    // 8. LayerNorm
    layernorm512<<<N, 256, 0, stream>>>(cbuf, ln_g, ln_b, (float*)d_out);

    (void)n_in; (void)out_size; (void)ws_size;
}

// Round 7
// 178.999 us; speedup vs baseline: 2.7113x; 1.0170x over previous
//
#include <hip/hip_runtime.h>

typedef __bf16 bf16;
typedef __attribute__((ext_vector_type(8))) __bf16 bf16x8;
typedef __attribute__((ext_vector_type(4))) float f32x4;
typedef __attribute__((ext_vector_type(4))) unsigned int u32x4;

#define DINC 256
#define HIDC 512
#define CAP  48    // fast-path max (deg+1): rows cached in LDS
#define MAXE 512   // mid-path max (deg+1): scores in LDS, global gather

__device__ __forceinline__ float lrelu02(float v) { return fmaxf(v, 0.2f * v); }

__device__ __forceinline__ void gload_lds16(const void* g, void* l) {
    __builtin_amdgcn_global_load_lds(
        (const __attribute__((address_space(1))) unsigned int*)g,
        (__attribute__((address_space(3))) unsigned int*)l, 16, 0, 0);
}

// ---------------------------------------------------------------------------
// bf16 MFMA GEMM body, 64x64 tile, BK=64. 256 thr = 4 waves, wave = 32x32.
// ---------------------------------------------------------------------------
__device__ __forceinline__ void gemm64_body(
    const bf16* __restrict__ A, const bf16* __restrict__ Bt,
    const float* __restrict__ bias, void* __restrict__ Cout,
    int K, int ldc, int col_off, int bx, int by, int relu, int outbf16,
    bf16* As, bf16* Bs)
{
    const int t = threadIdx.x;
    const int w = t >> 6, lane = t & 63;
    const long brow = (long)by * 64;
    const long bcol = (long)bx * 64;
    const int wr = (w >> 1) * 32, wc = (w & 1) * 32;
    const int fr = lane & 15, half = lane >> 4;
    const int srow = t >> 3;
    const int scol = (t & 7) * 8;

    const bf16* Ag = A  + (brow + srow) * K + scol;
    const bf16* Bg = Bt + (bcol + srow) * K + scol;
    const long rowK32 = (long)32 * K;

    f32x4 acc[2][2] = {};

    for (int k0 = 0; k0 < K; k0 += 64) {
        __syncthreads();
        gload_lds16(Ag + k0,          &As[t * 8]);
        gload_lds16(Ag + k0 + rowK32, &As[2048 + t * 8]);
        gload_lds16(Bg + k0,          &Bs[t * 8]);
        gload_lds16(Bg + k0 + rowK32, &Bs[2048 + t * 8]);
        __syncthreads();
#pragma unroll
        for (int ks = 0; ks < 2; ++ks) {
            bf16x8 af[2], bfr[2];
#pragma unroll
            for (int i = 0; i < 2; ++i)
                af[i] = *(const bf16x8*)&As[(wr + i * 16 + fr) * 64 + ks * 32 + half * 8];
#pragma unroll
            for (int j = 0; j < 2; ++j)
                bfr[j] = *(const bf16x8*)&Bs[(wc + j * 16 + fr) * 64 + ks * 32 + half * 8];
#pragma unroll
            for (int i = 0; i < 2; ++i)
#pragma unroll
                for (int j = 0; j < 2; ++j)
                    acc[i][j] = __builtin_amdgcn_mfma_f32_16x16x32_bf16(
                        af[i], bfr[j], acc[i][j], 0, 0, 0);
        }
    }

#pragma unroll
    for (int i = 0; i < 2; ++i) {
#pragma unroll
        for (int j = 0; j < 2; ++j) {
            const long gcol = bcol + wc + j * 16 + fr;
            const float bv = bias ? bias[gcol] : 0.0f;
#pragma unroll
            for (int v = 0; v < 4; ++v) {
                const long grow = brow + wr + i * 16 + half * 4 + v;
                float val = acc[i][j][v] + bv;
                if (relu) val = fmaxf(val, 0.0f);
                if (outbf16) ((bf16*)Cout)[grow * ldc + col_off + gcol] = (bf16)val;
                else         ((float*)Cout)[grow * ldc + col_off + gcol] = val;
            }
        }
    }
}

template<int RELU, int OUTBF16>
__global__ __launch_bounds__(256) void gemm64(
    const bf16* __restrict__ A, const bf16* __restrict__ Bt,
    const float* __restrict__ bias, void* __restrict__ Cout,
    int K, int ldc, int col_off)
{
    __shared__ bf16 As[64 * 64];
    __shared__ bf16 Bs[64 * 64];
    gemm64_body(A, Bt, bias, Cout, K, ldc, col_off,
                blockIdx.x, blockIdx.y, RELU, OUTBF16, As, Bs);
}

// ---------------------------------------------------------------------------
// mega_prep, grid (16,16,8): transposes, converts, fills, bias_comb.
// ---------------------------------------------------------------------------
__global__ __launch_bounds__(256) void mega_prep(
    const float* __restrict__ W_l, const float* __restrict__ W_r,
    const float* __restrict__ gin_W1, const float* __restrict__ fus_W,
    const float* __restrict__ gin_b2, const float* __restrict__ fus_b,
    const float* __restrict__ x, const float* __restrict__ W2,
    bf16* __restrict__ Wlr_t, bf16* __restrict__ W1t,
    bf16* __restrict__ Wfused_t, bf16* __restrict__ Wfbot_t,
    bf16* __restrict__ W2b, bf16* __restrict__ xb,
    float* __restrict__ bias_comb,
    u32x4* __restrict__ cnt, int cnt4, u32x4* __restrict__ bm, int bm4)
{
    const int z = blockIdx.z;
    const int t = threadIdx.x;
    if (z < 5) {
        const float* s; bf16* d; int K, Nc, ldd;
        switch (z) {
            case 0: s = W_l;            d = Wlr_t;         K = 256; Nc = 256; ldd = 256; break;
            case 1: s = W_r;            d = Wlr_t + 65536; K = 256; Nc = 256; ldd = 256; break;
            case 2: s = gin_W1;         d = W1t;           K = 256; Nc = 256; ldd = 256; break;
            case 3: s = fus_W;          d = Wfused_t;      K = 256; Nc = 512; ldd = 512; break;
            default: s = fus_W + 256 * 512; d = Wfbot_t;   K = 256; Nc = 512; ldd = 256; break;
        }
        const int bn = blockIdx.x * 32, bk = blockIdx.y * 32;
        if (bn >= Nc || bk >= K) return;
        __shared__ float tile[32][33];
        const int tx = t & 31, ty = t >> 5;
#pragma unroll
        for (int r = 0; r < 32; r += 8)
            tile[ty + r][tx] = s[(size_t)(bk + ty + r) * Nc + bn + tx];
        __syncthreads();
#pragma unroll
        for (int r = 0; r < 32; r += 8)
            d[(size_t)(bn + ty + r) * ldd + bk + tx] = (bf16)tile[tx][ty + r];
        return;
    }
    const int bid = blockIdx.y * 16 + blockIdx.x;
    if (z == 5) {
        if (bid >= 32) return;
        const int u = bid * 256 + t;
        const float4* wv = (const float4*)W2;
        float4 a = wv[(size_t)u * 2], b = wv[(size_t)u * 2 + 1];
        bf16x8 o;
        o[0] = (bf16)a.x; o[1] = (bf16)a.y; o[2] = (bf16)a.z; o[3] = (bf16)a.w;
        o[4] = (bf16)b.x; o[5] = (bf16)b.y; o[6] = (bf16)b.z; o[7] = (bf16)b.w;
        *(bf16x8*)&W2b[(size_t)u * 8] = o;
        return;
    }
    if (z == 6) {
        const int u0 = bid * 256 + t;
        const float4* xv = (const float4*)x;
#pragma unroll
        for (int r = 0; r < 4; ++r) {
            const int u = u0 + r * 65536;
            float4 a = xv[(size_t)u * 2], b = xv[(size_t)u * 2 + 1];
            bf16x8 o;
            o[0] = (bf16)a.x; o[1] = (bf16)a.y; o[2] = (bf16)a.z; o[3] = (bf16)a.w;
            o[4] = (bf16)b.x; o[5] = (bf16)b.y; o[6] = (bf16)b.z; o[7] = (bf16)b.w;
            *(bf16x8*)&xb[(size_t)u * 8] = o;
        }
        return;
    }
    // z == 7: bias_comb + zero fills
    const int gid = bid * 256 + t;
    if (gid < 512) {
        float acc = fus_b[gid];
        for (int j = 0; j < 256; ++j)
            acc += gin_b2[j] * fus_W[(size_t)(256 + j) * 512 + gid];
        bias_comb[gid] = acc;
    }
    const int stride = 256 * 256;
    const u32x4 zv = {0u, 0u, 0u, 0u};
    for (int i = gid; i < cnt4; i += stride) cnt[i] = zv;
    for (int i = gid; i < bm4; i += stride) bm[i] = zv;
}

// ---------------------------------------------------------------------------
// CSR build
// ---------------------------------------------------------------------------
__global__ __launch_bounds__(256) void build_hist(
    const int* __restrict__ src, const int* __restrict__ dst, int E, int N,
    int* __restrict__ cnt_dst, int* __restrict__ cnt_src,
    unsigned int* __restrict__ bitmap, unsigned char* __restrict__ flags)
{
    int e = blockIdx.x * 256 + threadIdx.x;
    if (e >= E) return;
    int s = src[e], d = dst[e];
    atomicAdd(&cnt_dst[d], 1);
    unsigned int key  = (unsigned int)s * (unsigned int)N + (unsigned int)d;
    unsigned int word = key >> 5;
    unsigned int bit  = 1u << (key & 31u);
    unsigned int old  = atomicOr(&bitmap[word], bit);
    int own = (old & bit) == 0u;
    flags[e] = (unsigned char)own;
    if (own) atomicAdd(&cnt_src[s], 1);
}

__global__ __launch_bounds__(1024) void scan_both(
    const int* __restrict__ cnt_dst, int* __restrict__ off_dst, int* __restrict__ cur_dst,
    const int* __restrict__ cnt_src, int* __restrict__ off_src, int* __restrict__ cur_src)
{
    const int* cnt = blockIdx.x ? cnt_src : cnt_dst;
    int* off = blockIdx.x ? off_src : off_dst;
    int* cur = blockIdx.x ? cur_src : cur_dst;
    __shared__ int lds[1024];
    const int t = threadIdx.x;
    const int base = t * 8;
    int v[8]; int s = 0;
#pragma unroll
    for (int j = 0; j < 8; ++j) { v[j] = cnt[base + j]; s += v[j]; }
    lds[t] = s;
    __syncthreads();
    int mine = s;
    for (int o = 1; o < 1024; o <<= 1) {
        int add = (t >= o) ? lds[t - o] : 0;
        __syncthreads();
        lds[t] += add;
        __syncthreads();
    }
    int run = lds[t] - mine;
#pragma unroll
    for (int j = 0; j < 8; ++j) { off[base + j] = run; cur[base + j] = run; run += v[j]; }
    if (t == 1023) off[8192] = run;
}

// ---------------------------------------------------------------------------
// Heterogeneous: scatter | xlr GEMM | Wcomb GEMM
// ---------------------------------------------------------------------------
__global__ __launch_bounds__(256) void scatter_gemms(
    const int* __restrict__ src, const int* __restrict__ dst, int E,
    int* __restrict__ cur_dst, int* __restrict__ cur_src,
    const unsigned char* __restrict__ flags,
    int* __restrict__ csr_src, int* __restrict__ csr_gin,
    const bf16* __restrict__ xb, const bf16* __restrict__ Wlr_t,
    bf16* __restrict__ xlr,
    const bf16* __restrict__ Wfbot_t, const bf16* __restrict__ W2b,
    bf16* __restrict__ Wfused_t)
{
    __shared__ bf16 As[64 * 64];
    __shared__ bf16 Bs[64 * 64];
    const int nsc = (E + 255) >> 8;
    int bid = blockIdx.x;
    if (bid < nsc) {
        int e = bid * 256 + threadIdx.x;
        if (e >= E) return;
        int s = src[e], d = dst[e];
        int p = atomicAdd(&cur_dst[d], 1);
        csr_src[p] = s;
        if (flags[e]) {
            int q = atomicAdd(&cur_src[s], 1);
            csr_gin[q] = d;
        }
        return;
    }
    bid -= nsc;
    if (bid < 1024) {
        gemm64_body(xb, Wlr_t, nullptr, xlr, 256, HIDC, 0,
                    bid & 7, bid >> 3, 0, 1, As, Bs);
        return;
    }
    bid -= 1024;
    gemm64_body(Wfbot_t, W2b, nullptr, Wfused_t, 256, HIDC, 256,
                bid & 3, bid >> 2, 0, 1, As, Bs);
}

// ---------------------------------------------------------------------------
// Merged GAT (blocks 0..N-1) + GIN aggregate (blocks N..2N-1).
// Vectorized inner loops: thread = (edge-slot e8, feature-group g of 8).
// ---------------------------------------------------------------------------
__global__ __launch_bounds__(256) void gatgin(
    const bf16* __restrict__ xlr, const int* __restrict__ csr_src,
    const int* __restrict__ off_dst, const float* __restrict__ att,
    const float* __restrict__ b_gat, bf16* __restrict__ cat,
    const bf16* __restrict__ xb, const int* __restrict__ csr_gin,
    const int* __restrict__ off_src, bf16* __restrict__ hbuf, int N)
{
    __shared__ __align__(16) char lds_raw[CAP * 512];  // rows[CAP][256]bf16 / ssc / red[8][256]f32
    __shared__ float sc[4 * CAP];
    __shared__ float sden[4];
    const int t = threadIdx.x;
    const int e8 = t >> 5, g = t & 31;

    if (blockIdx.x >= N) {
        // ---------------- GIN aggregate (vectorized b128 gathers) ----------
        const int i = blockIdx.x - N;
        const int beg = off_src[i], end = off_src[i + 1];
        float a0 = 0, a1 = 0, a2 = 0, a3 = 0, a4 = 0, a5 = 0, a6 = 0, a7 = 0;
        if (e8 == 0) {
            bf16x8 xv = *(const bf16x8*)&xb[(size_t)i * DINC + g * 8];
            a0 = (float)xv[0]; a1 = (float)xv[1]; a2 = (float)xv[2]; a3 = (float)xv[3];
            a4 = (float)xv[4]; a5 = (float)xv[5]; a6 = (float)xv[6]; a7 = (float)xv[7];
        }
        for (int j = beg + e8; j < end; j += 8) {
            const int s = csr_gin[j];
            bf16x8 v = *(const bf16x8*)&xb[(size_t)s * DINC + g * 8];
            a0 += (float)v[0]; a1 += (float)v[1]; a2 += (float)v[2]; a3 += (float)v[3];
            a4 += (float)v[4]; a5 += (float)v[5]; a6 += (float)v[6]; a7 += (float)v[7];
        }
        float* red = (float*)lds_raw;           // [8][256]
        f32x4 lo = {a0, a1, a2, a3}, hi = {a4, a5, a6, a7};
        *(f32x4*)&red[e8 * 256 + g * 8]     = lo;
        *(f32x4*)&red[e8 * 256 + g * 8 + 4] = hi;
        __syncthreads();
        float acc = 0.0f;
#pragma unroll
        for (int s = 0; s < 8; ++s) acc += red[s * 256 + t];
        hbuf[(size_t)i * DINC + t] = (bf16)acc;
        return;
    }

    // ---------------- GATv2 ----------------
    bf16* rows = (bf16*)lds_raw;
    float* ssc = (float*)lds_raw;
    const int d = blockIdx.x;
    const int beg = off_dst[d];
    const int deg = off_dst[d + 1] - beg;
    const int cnt = deg + 1;

    if (cnt <= CAP) {
        const int h8 = g >> 3;
        float xr8[8], at8[8];
        {
            bf16x8 xv = *(const bf16x8*)&xlr[(size_t)d * HIDC + 256 + g * 8];
#pragma unroll
            for (int f = 0; f < 8; ++f) xr8[f] = (float)xv[f];
            float4 q0 = *(const float4*)&att[g * 8];
            float4 q1 = *(const float4*)&att[g * 8 + 4];
            at8[0] = q0.x; at8[1] = q0.y; at8[2] = q0.z; at8[3] = q0.w;
            at8[4] = q1.x; at8[5] = q1.y; at8[6] = q1.z; at8[7] = q1.w;
        }
        // phase 1: scores + row cache, 16 rows in flight
        for (int base = 0; base < cnt; base += 16) {
            const int j0 = base + e8, j1 = base + 8 + e8;
            const int s0 = (j0 < deg) ? csr_src[beg + j0] : d;
            const int s1 = (j1 < deg) ? csr_src[beg + j1] : d;
            bf16x8 v0 = *(const bf16x8*)&xlr[(size_t)s0 * HIDC + g * 8];
            bf16x8 v1 = *(const bf16x8*)&xlr[(size_t)s1 * HIDC + g * 8];
            float p0 = 0.0f, p1 = 0.0f;
#pragma unroll
            for (int f = 0; f < 8; ++f) {
                p0 += lrelu02((float)v0[f] + xr8[f]) * at8[f];
                p1 += lrelu02((float)v1[f] + xr8[f]) * at8[f];
            }
            p0 += __shfl_xor(p0, 1); p1 += __shfl_xor(p1, 1);
            p0 += __shfl_xor(p0, 2); p1 += __shfl_xor(p1, 2);
            p0 += __shfl_xor(p0, 4); p1 += __shfl_xor(p1, 4);
            if (j0 < cnt) {
                *(bf16x8*)&rows[j0 * 256 + g * 8] = v0;
                if ((g & 7) == 0) sc[h8 * CAP + j0] = p0;
            }
            if (j1 < cnt) {
                *(bf16x8*)&rows[j1 * 256 + g * 8] = v1;
                if ((g & 7) == 0) sc[h8 * CAP + j1] = p1;
            }
        }
        __syncthreads();
        // phase 2: per-head softmax weights (cnt <= 48 < 64)
        {
            const int h = t >> 6, k = t & 63;
            float m = (k < cnt) ? sc[h * CAP + k] : -1e30f;
#pragma unroll
            for (int o = 1; o < 64; o <<= 1) m = fmaxf(m, __shfl_xor(m, o));
            float ds = 0.0f;
            if (k < cnt) {
                ds = __expf(sc[h * CAP + k] - m);
                sc[h * CAP + k] = ds;
            }
#pragma unroll
            for (int o = 1; o < 64; o <<= 1) ds += __shfl_xor(ds, o);
            if (k == 0) sden[h] = ds;
        }
        __syncthreads();
        // phase 3: vectorized weighted aggregation (b128 LDS reads)
        float a0 = 0, a1 = 0, a2 = 0, a3 = 0, a4 = 0, a5 = 0, a6 = 0, a7 = 0;
        {
            const float* wrow = &sc[(g >> 3) * CAP];
            for (int jj = e8; jj < cnt; jj += 8) {
                const float wj = wrow[jj];
                bf16x8 rv = *(const bf16x8*)&rows[jj * 256 + g * 8];
                a0 = fmaf(wj, (float)rv[0], a0); a1 = fmaf(wj, (float)rv[1], a1);
                a2 = fmaf(wj, (float)rv[2], a2); a3 = fmaf(wj, (float)rv[3], a3);
                a4 = fmaf(wj, (float)rv[4], a4); a5 = fmaf(wj, (float)rv[5], a5);
                a6 = fmaf(wj, (float)rv[6], a6); a7 = fmaf(wj, (float)rv[7], a7);
            }
        }
        __syncthreads();                        // all rows reads done
        float* red = (float*)lds_raw;           // reuse rows region: [8][256]
        f32x4 lo = {a0, a1, a2, a3}, hi = {a4, a5, a6, a7};
        *(f32x4*)&red[e8 * 256 + g * 8]     = lo;
        *(f32x4*)&red[e8 * 256 + g * 8 + 4] = hi;
        __syncthreads();
        float acc = 0.0f;
#pragma unroll
        for (int s = 0; s < 8; ++s) acc += red[s * 256 + t];
        cat[(size_t)d * HIDC + t] = (bf16)(acc / sden[t >> 6] + b_gat[t]);
        return;
    }

    if (cnt <= MAXE) {
        const int h8 = g >> 3;
        float xr8[8], at8[8];
        {
            bf16x8 xv = *(const bf16x8*)&xlr[(size_t)d * HIDC + 256 + g * 8];
#pragma unroll
            for (int f = 0; f < 8; ++f) xr8[f] = (float)xv[f];
            float4 q0 = *(const float4*)&att[g * 8];
            float4 q1 = *(const float4*)&att[g * 8 + 4];
            at8[0] = q0.x; at8[1] = q0.y; at8[2] = q0.z; at8[3] = q0.w;
            at8[4] = q1.x; at8[5] = q1.y; at8[6] = q1.z; at8[7] = q1.w;
        }
        for (int base = 0; base < cnt; base += 8) {
            const int jj = base + e8;
            int s = d;
            if (jj < deg) s = csr_src[beg + jj];
            bf16x8 xv = *(const bf16x8*)&xlr[(size_t)s * HIDC + g * 8];
            float p = 0.0f;
#pragma unroll
            for (int f = 0; f < 8; ++f)
                p += lrelu02((float)xv[f] + xr8[f]) * at8[f];
            p += __shfl_xor(p, 1);
            p += __shfl_xor(p, 2);
            p += __shfl_xor(p, 4);
            if (jj < cnt && (g & 7) == 0) ssc[h8 * MAXE + jj] = p;
        }
        __syncthreads();
        {
            const int h = t >> 6, k = t & 63;
            float m = -1e30f;
            for (int jj = k; jj < cnt; jj += 64) m = fmaxf(m, ssc[h * MAXE + jj]);
#pragma unroll
            for (int o = 1; o < 64; o <<= 1) m = fmaxf(m, __shfl_xor(m, o));
            float ds = 0.0f;
            for (int jj = k; jj < cnt; jj += 64) {
                float wgt = __expf(ssc[h * MAXE + jj] - m);
                ssc[h * MAXE + jj] = wgt;
                ds += wgt;
            }
#pragma unroll
            for (int o = 1; o < 64; o <<= 1) ds += __shfl_xor(ds, o);
            if (k == 0) sden[h] = ds;
        }
        __syncthreads();
        const int h = t >> 6;
        const float* wrow = &ssc[h * MAXE];
        float acc = 0.0f;
        int jj = 0;
        for (; jj + 4 <= cnt; jj += 4) {
            const int s0 = (jj     < deg) ? csr_src[beg + jj]     : d;
            const int s1 = (jj + 1 < deg) ? csr_src[beg + jj + 1] : d;
            const int s2 = (jj + 2 < deg) ? csr_src[beg + jj + 2] : d;
            const int s3 = (jj + 3 < deg) ? csr_src[beg + jj + 3] : d;
            const float v0 = (float)xlr[(size_t)s0 * HIDC + t];
            const float v1 = (float)xlr[(size_t)s1 * HIDC + t];
            const float v2 = (float)xlr[(size_t)s2 * HIDC + t];
            const float v3 = (float)xlr[(size_t)s3 * HIDC + t];
            acc = fmaf(wrow[jj], v0, acc);
            acc = fmaf(wrow[jj + 1], v1, acc);
            acc = fmaf(wrow[jj + 2], v2, acc);
            acc = fmaf(wrow[jj + 3], v3, acc);
        }
        for (; jj < cnt; ++jj) {
            const int s = (jj < deg) ? csr_src[beg + jj] : d;
            acc = fmaf(wrow[jj], (float)xlr[(size_t)s * HIDC + t], acc);
        }
        cat[(size_t)d * HIDC + t] = (bf16)(acc / sden[h] + b_gat[t]);
        return;
    }

    {   // serial fallback
        const float attv = att[t];
        const float xrv = (float)xlr[(size_t)d * HIDC + 256 + t];
        const float xld = (float)xlr[(size_t)d * HIDC + t];
        float p = lrelu02(xld + xrv) * attv;
#pragma unroll
        for (int o = 1; o < 64; o <<= 1) p += __shfl_xor(p, o);
        float m = p, denom = 1.0f, acc = xld;
        for (int j = beg; j < beg + deg; ++j) {
            const int s = csr_src[j];
            const float xls = (float)xlr[(size_t)s * HIDC + t];
            float q = lrelu02(xls + xrv) * attv;
#pragma unroll
            for (int o = 1; o < 64; o <<= 1) q += __shfl_xor(q, o);
            if (q > m) {
                const float r = __expf(m - q);
                denom = denom * r + 1.0f;
                acc   = acc * r + xls;
                m = q;
            } else {
                const float wgt = __expf(q - m);
                denom += wgt;
                acc   += wgt * xls;
            }
        }
        cat[(size_t)d * HIDC + t] = (bf16)(acc / denom + b_gat[t]);
    }
}

// LayerNorm over 512 features (bf16 in, fp32 out)
__global__ __launch_bounds__(256) void layernorm512(
    const bf16* __restrict__ cbuf, const float* __restrict__ g,
    const float* __restrict__ b, float* __restrict__ out)
{
    const int r = blockIdx.x;
    const int t = threadIdx.x;
    typedef __attribute__((ext_vector_type(2))) __bf16 bf16x2;
    bf16x2 pv = *(const bf16x2*)&cbuf[(size_t)r * HIDC + t * 2];
    float v0 = (float)pv[0], v1 = (float)pv[1];
    float s = v0 + v1;
    float q = v0 * v0 + v1 * v1;
    for (int o = 1; o < 64; o <<= 1) {
        s += __shfl_xor(s, o);
        q += __shfl_xor(q, o);
    }
    __shared__ float ls[4], lq[4];
    int w = t >> 6;
    if ((t & 63) == 0) { ls[w] = s; lq[w] = q; }
    __syncthreads();
    s = ls[0] + ls[1] + ls[2] + ls[3];
    q = lq[0] + lq[1] + lq[2] + lq[3];
    float mu  = s * (1.0f / 512.0f);
    float var = q * (1.0f / 512.0f) - mu * mu;
    float rs  = rsqrtf(var + 1e-5f);
    int c0 = t * 2;
    out[(size_t)r * HIDC + c0]     = (v0 - mu) * rs * g[c0]     + b[c0];
    out[(size_t)r * HIDC + c0 + 1] = (v1 - mu) * rs * g[c0 + 1] + b[c0 + 1];
}

// ---------------------------------------------------------------------------
extern "C" void kernel_launch(void* const* d_in, const int* in_sizes, int n_in,
                              void* d_out, int out_size, void* d_ws, size_t ws_size,
                              hipStream_t stream)
{
    const float* x      = (const float*)d_in[0];
    const float* W_l    = (const float*)d_in[1];
    const float* W_r    = (const float*)d_in[2];
    const float* att    = (const float*)d_in[3];
    const float* b_gat  = (const float*)d_in[4];
    const float* gin_W1 = (const float*)d_in[5];
    const float* gin_b1 = (const float*)d_in[6];
    const float* gin_W2 = (const float*)d_in[7];
    const float* gin_b2 = (const float*)d_in[8];
    const float* fus_W  = (const float*)d_in[9];
    const float* fus_b  = (const float*)d_in[10];
    const float* ln_g   = (const float*)d_in[11];
    const float* ln_b   = (const float*)d_in[12];
    const int*   eidx   = (const int*)d_in[13];

    const int E = in_sizes[13] / 2;
    const int N = in_sizes[0] / DINC;  // 8192
    const int* src = eidx;
    const int* dst = eidx + E;

    char* ws = (char*)d_ws;
    size_t off = 0;
    auto alloc = [&](size_t bytes) -> void* {
        void* p = ws + off;
        off = (off + bytes + 255) & ~(size_t)255;
        return p;
    };
    bf16* xb       = (bf16*)alloc((size_t)N * DINC * 2);
    bf16* xlr      = (bf16*)alloc((size_t)N * HIDC * 2);
    bf16* Wlr_t    = (bf16*)alloc((size_t)512 * 256 * 2);
    bf16* W1t      = (bf16*)alloc((size_t)256 * 256 * 2);
    bf16* Wfused_t = (bf16*)alloc((size_t)512 * 512 * 2);
    bf16* Wfbot_t  = (bf16*)alloc((size_t)512 * 256 * 2);
    bf16* W2b      = (bf16*)alloc((size_t)256 * 256 * 2);
    bf16* hbuf     = (bf16*)alloc((size_t)N * DINC * 2);
    bf16* cat      = (bf16*)alloc((size_t)N * HIDC * 2);
    bf16* cbuf     = (bf16*)alloc((size_t)N * HIDC * 2);
    float* bias_comb = (float*)alloc(512 * 4);
    int* cnt_dst = (int*)alloc((size_t)N * 4);   // cnt_dst+cnt_src contiguous
    int* cnt_src = (int*)alloc((size_t)N * 4);
    int* off_dst = (int*)alloc((size_t)(N + 1) * 4);
    int* cur_dst = (int*)alloc((size_t)N * 4);
    int* off_src = (int*)alloc((size_t)(N + 1) * 4);
    int* cur_src = (int*)alloc((size_t)N * 4);
    int* csr_src = (int*)alloc((size_t)E * 4);
    int* csr_gin = (int*)alloc((size_t)E * 4);
    unsigned char* flags  = (unsigned char*)alloc((size_t)E);
    unsigned int*  bitmap = (unsigned int*)alloc((size_t)N * (size_t)N / 8);

    mega_prep<<<dim3(16, 16, 8), 256, 0, stream>>>(
        W_l, W_r, gin_W1, fus_W, gin_b2, fus_b, x, gin_W2,
        Wlr_t, W1t, Wfused_t, Wfbot_t, W2b, xb, bias_comb,
        (u32x4*)cnt_dst, (2 * N) / 4,
        (u32x4*)bitmap, (int)((size_t)N * N / 32 / 4));

    build_hist<<<(E + 255) / 256, 256, 0, stream>>>(src, dst, E, N, cnt_dst, cnt_src, bitmap, flags);
    scan_both<<<2, 1024, 0, stream>>>(cnt_dst, off_dst, cur_dst, cnt_src, off_src, cur_src);

    const int nsc = (E + 255) / 256;
    scatter_gemms<<<nsc + 1024 + 32, 256, 0, stream>>>(
        src, dst, E, cur_dst, cur_src, flags, csr_src, csr_gin,
        xb, Wlr_t, xlr, Wfbot_t, W2b, Wfused_t);

    gatgin<<<2 * N, 256, 0, stream>>>(xlr, csr_src, off_dst, att, b_gat, cat,
                                      xb, csr_gin, off_src, hbuf, N);

    gemm64<1, 1><<<dim3(4, 128), 256, 0, stream>>>(hbuf, W1t, gin_b1, cat, 256, HIDC, 256);
    gemm64<1, 1><<<dim3(8, 128), 256, 0, stream>>>(cat, Wfused_t, bias_comb, cbuf, 512, HIDC, 0);
    layernorm512<<<N, 256, 0, stream>>>(cbuf, ln_g, ln_b, (float*)d_out);

    (void)n_in; (void)out_size; (void)ws_size;
}

// Round 8
// 169.669 us; speedup vs baseline: 2.8604x; 1.0550x over previous
//
#include <hip/hip_runtime.h>

typedef __bf16 bf16;
typedef __attribute__((ext_vector_type(8))) __bf16 bf16x8;
typedef __attribute__((ext_vector_type(4))) float f32x4;
typedef __attribute__((ext_vector_type(4))) unsigned int u32x4;

#define DINC 256
#define HIDC 512

__device__ __forceinline__ float lrelu02(float v) { return fmaxf(v, 0.2f * v); }

__device__ __forceinline__ void gload_lds16(const void* g, void* l) {
    __builtin_amdgcn_global_load_lds(
        (const __attribute__((address_space(1))) unsigned int*)g,
        (__attribute__((address_space(3))) unsigned int*)l, 16, 0, 0);
}

// ---------------------------------------------------------------------------
// bf16 MFMA GEMM body, 64x64 tile, BK=64. 256 thr = 4 waves, wave = 32x32.
// ---------------------------------------------------------------------------
__device__ __forceinline__ void gemm64_body(
    const bf16* __restrict__ A, const bf16* __restrict__ Bt,
    const float* __restrict__ bias, void* __restrict__ Cout,
    int K, int ldc, int col_off, int bx, int by, int relu, int outbf16,
    bf16* As, bf16* Bs)
{
    const int t = threadIdx.x;
    const int w = t >> 6, lane = t & 63;
    const long brow = (long)by * 64;
    const long bcol = (long)bx * 64;
    const int wr = (w >> 1) * 32, wc = (w & 1) * 32;
    const int fr = lane & 15, half = lane >> 4;
    const int srow = t >> 3;
    const int scol = (t & 7) * 8;

    const bf16* Ag = A  + (brow + srow) * K + scol;
    const bf16* Bg = Bt + (bcol + srow) * K + scol;
    const long rowK32 = (long)32 * K;

    f32x4 acc[2][2] = {};

    for (int k0 = 0; k0 < K; k0 += 64) {
        __syncthreads();
        gload_lds16(Ag + k0,          &As[t * 8]);
        gload_lds16(Ag + k0 + rowK32, &As[2048 + t * 8]);
        gload_lds16(Bg + k0,          &Bs[t * 8]);
        gload_lds16(Bg + k0 + rowK32, &Bs[2048 + t * 8]);
        __syncthreads();
#pragma unroll
        for (int ks = 0; ks < 2; ++ks) {
            bf16x8 af[2], bfr[2];
#pragma unroll
            for (int i = 0; i < 2; ++i)
                af[i] = *(const bf16x8*)&As[(wr + i * 16 + fr) * 64 + ks * 32 + half * 8];
#pragma unroll
            for (int j = 0; j < 2; ++j)
                bfr[j] = *(const bf16x8*)&Bs[(wc + j * 16 + fr) * 64 + ks * 32 + half * 8];
#pragma unroll
            for (int i = 0; i < 2; ++i)
#pragma unroll
                for (int j = 0; j < 2; ++j)
                    acc[i][j] = __builtin_amdgcn_mfma_f32_16x16x32_bf16(
                        af[i], bfr[j], acc[i][j], 0, 0, 0);
        }
    }

#pragma unroll
    for (int i = 0; i < 2; ++i) {
#pragma unroll
        for (int j = 0; j < 2; ++j) {
            const long gcol = bcol + wc + j * 16 + fr;
            const float bv = bias ? bias[gcol] : 0.0f;
#pragma unroll
            for (int v = 0; v < 4; ++v) {
                const long grow = brow + wr + i * 16 + half * 4 + v;
                float val = acc[i][j][v] + bv;
                if (relu) val = fmaxf(val, 0.0f);
                if (outbf16) ((bf16*)Cout)[grow * ldc + col_off + gcol] = (bf16)val;
                else         ((float*)Cout)[grow * ldc + col_off + gcol] = val;
            }
        }
    }
}

template<int RELU, int OUTBF16>
__global__ __launch_bounds__(256) void gemm64(
    const bf16* __restrict__ A, const bf16* __restrict__ Bt,
    const float* __restrict__ bias, void* __restrict__ Cout,
    int K, int ldc, int col_off)
{
    __shared__ bf16 As[64 * 64];
    __shared__ bf16 Bs[64 * 64];
    gemm64_body(A, Bt, bias, Cout, K, ldc, col_off,
                blockIdx.x, blockIdx.y, RELU, OUTBF16, As, Bs);
}

// ---------------------------------------------------------------------------
// mega_prep, grid (16,16,8): transposes, converts, fills, bias_comb.
// ---------------------------------------------------------------------------
__global__ __launch_bounds__(256) void mega_prep(
    const float* __restrict__ W_l, const float* __restrict__ W_r,
    const float* __restrict__ gin_W1, const float* __restrict__ fus_W,
    const float* __restrict__ gin_b2, const float* __restrict__ fus_b,
    const float* __restrict__ x, const float* __restrict__ W2,
    bf16* __restrict__ Wlr_t, bf16* __restrict__ W1t,
    bf16* __restrict__ Wfused_t, bf16* __restrict__ Wfbot_t,
    bf16* __restrict__ W2b, bf16* __restrict__ xb,
    float* __restrict__ bias_comb,
    u32x4* __restrict__ cnt, int cnt4, u32x4* __restrict__ bm, int bm4)
{
    const int z = blockIdx.z;
    const int t = threadIdx.x;
    if (z < 5) {
        const float* s; bf16* d; int K, Nc, ldd;
        switch (z) {
            case 0: s = W_l;            d = Wlr_t;         K = 256; Nc = 256; ldd = 256; break;
            case 1: s = W_r;            d = Wlr_t + 65536; K = 256; Nc = 256; ldd = 256; break;
            case 2: s = gin_W1;         d = W1t;           K = 256; Nc = 256; ldd = 256; break;
            case 3: s = fus_W;          d = Wfused_t;      K = 256; Nc = 512; ldd = 512; break;
            default: s = fus_W + 256 * 512; d = Wfbot_t;   K = 256; Nc = 512; ldd = 256; break;
        }
        const int bn = blockIdx.x * 32, bk = blockIdx.y * 32;
        if (bn >= Nc || bk >= K) return;
        __shared__ float tile[32][33];
        const int tx = t & 31, ty = t >> 5;
#pragma unroll
        for (int r = 0; r < 32; r += 8)
            tile[ty + r][tx] = s[(size_t)(bk + ty + r) * Nc + bn + tx];
        __syncthreads();
#pragma unroll
        for (int r = 0; r < 32; r += 8)
            d[(size_t)(bn + ty + r) * ldd + bk + tx] = (bf16)tile[tx][ty + r];
        return;
    }
    const int bid = blockIdx.y * 16 + blockIdx.x;
    if (z == 5) {
        if (bid >= 32) return;
        const int u = bid * 256 + t;
        const float4* wv = (const float4*)W2;
        float4 a = wv[(size_t)u * 2], b = wv[(size_t)u * 2 + 1];
        bf16x8 o;
        o[0] = (bf16)a.x; o[1] = (bf16)a.y; o[2] = (bf16)a.z; o[3] = (bf16)a.w;
        o[4] = (bf16)b.x; o[5] = (bf16)b.y; o[6] = (bf16)b.z; o[7] = (bf16)b.w;
        *(bf16x8*)&W2b[(size_t)u * 8] = o;
        return;
    }
    if (z == 6) {
        const int u0 = bid * 256 + t;
        const float4* xv = (const float4*)x;
#pragma unroll
        for (int r = 0; r < 4; ++r) {
            const int u = u0 + r * 65536;
            float4 a = xv[(size_t)u * 2], b = xv[(size_t)u * 2 + 1];
            bf16x8 o;
            o[0] = (bf16)a.x; o[1] = (bf16)a.y; o[2] = (bf16)a.z; o[3] = (bf16)a.w;
            o[4] = (bf16)b.x; o[5] = (bf16)b.y; o[6] = (bf16)b.z; o[7] = (bf16)b.w;
            *(bf16x8*)&xb[(size_t)u * 8] = o;
        }
        return;
    }
    // z == 7: bias_comb + zero fills
    const int gid = bid * 256 + t;
    if (gid < 512) {
        float acc = fus_b[gid];
        for (int j = 0; j < 256; ++j)
            acc += gin_b2[j] * fus_W[(size_t)(256 + j) * 512 + gid];
        bias_comb[gid] = acc;
    }
    const int stride = 256 * 256;
    const u32x4 zv = {0u, 0u, 0u, 0u};
    for (int i = gid; i < cnt4; i += stride) cnt[i] = zv;
    for (int i = gid; i < bm4; i += stride) bm[i] = zv;
}

// ---------------------------------------------------------------------------
// CSR build
// ---------------------------------------------------------------------------
__global__ __launch_bounds__(256) void build_hist(
    const int* __restrict__ src, const int* __restrict__ dst, int E, int N,
    int* __restrict__ cnt_dst, int* __restrict__ cnt_src,
    unsigned int* __restrict__ bitmap, unsigned char* __restrict__ flags)
{
    int e = blockIdx.x * 256 + threadIdx.x;
    if (e >= E) return;
    int s = src[e], d = dst[e];
    atomicAdd(&cnt_dst[d], 1);
    unsigned int key  = (unsigned int)s * (unsigned int)N + (unsigned int)d;
    unsigned int word = key >> 5;
    unsigned int bit  = 1u << (key & 31u);
    unsigned int old  = atomicOr(&bitmap[word], bit);
    int own = (old & bit) == 0u;
    flags[e] = (unsigned char)own;
    if (own) atomicAdd(&cnt_src[s], 1);
}

__global__ __launch_bounds__(1024) void scan_both(
    const int* __restrict__ cnt_dst, int* __restrict__ off_dst, int* __restrict__ cur_dst,
    const int* __restrict__ cnt_src, int* __restrict__ off_src, int* __restrict__ cur_src)
{
    const int* cnt = blockIdx.x ? cnt_src : cnt_dst;
    int* off = blockIdx.x ? off_src : off_dst;
    int* cur = blockIdx.x ? cur_src : cur_dst;
    __shared__ int lds[1024];
    const int t = threadIdx.x;
    const int base = t * 8;
    int v[8]; int s = 0;
#pragma unroll
    for (int j = 0; j < 8; ++j) { v[j] = cnt[base + j]; s += v[j]; }
    lds[t] = s;
    __syncthreads();
    int mine = s;
    for (int o = 1; o < 1024; o <<= 1) {
        int add = (t >= o) ? lds[t - o] : 0;
        __syncthreads();
        lds[t] += add;
        __syncthreads();
    }
    int run = lds[t] - mine;
#pragma unroll
    for (int j = 0; j < 8; ++j) { off[base + j] = run; cur[base + j] = run; run += v[j]; }
    if (t == 1023) off[8192] = run;
}

// ---------------------------------------------------------------------------
// Heterogeneous: scatter | xlr GEMM | Wcomb GEMM
// ---------------------------------------------------------------------------
__global__ __launch_bounds__(256) void scatter_gemms(
    const int* __restrict__ src, const int* __restrict__ dst, int E,
    int* __restrict__ cur_dst, int* __restrict__ cur_src,
    const unsigned char* __restrict__ flags,
    int* __restrict__ csr_src, int* __restrict__ csr_gin,
    const bf16* __restrict__ xb, const bf16* __restrict__ Wlr_t,
    bf16* __restrict__ xlr,
    const bf16* __restrict__ Wfbot_t, const bf16* __restrict__ W2b,
    bf16* __restrict__ Wfused_t)
{
    __shared__ bf16 As[64 * 64];
    __shared__ bf16 Bs[64 * 64];
    const int nsc = (E + 255) >> 8;
    int bid = blockIdx.x;
    if (bid < nsc) {
        int e = bid * 256 + threadIdx.x;
        if (e >= E) return;
        int s = src[e], d = dst[e];
        int p = atomicAdd(&cur_dst[d], 1);
        csr_src[p] = s;
        if (flags[e]) {
            int q = atomicAdd(&cur_src[s], 1);
            csr_gin[q] = d;
        }
        return;
    }
    bid -= nsc;
    if (bid < 1024) {
        gemm64_body(xb, Wlr_t, nullptr, xlr, 256, HIDC, 0,
                    bid & 7, bid >> 3, 0, 1, As, Bs);
        return;
    }
    bid -= 1024;
    gemm64_body(Wfbot_t, W2b, nullptr, Wfused_t, 256, HIDC, 256,
                bid & 3, bid >> 2, 0, 1, As, Bs);
}

// ---------------------------------------------------------------------------
// Merged GAT (blocks 0..N-1) + GIN aggregate (blocks N..2N-1).
// GAT: single-pass online softmax per (edge-slot e8, feature-group g).
// Each thread keeps running (m, denom, acc[8]); one gather per edge;
// cross-slot combine via 8x256 f32 LDS + exp(m_s - M) rescale.
// Works for ANY degree (no path split). LDS 8.4 KB -> 8 blocks/CU.
// ---------------------------------------------------------------------------
__global__ __launch_bounds__(256, 8) void gatgin(
    const bf16* __restrict__ xlr, const int* __restrict__ csr_src,
    const int* __restrict__ off_dst, const float* __restrict__ att,
    const float* __restrict__ b_gat, bf16* __restrict__ cat,
    const bf16* __restrict__ xb, const int* __restrict__ csr_gin,
    const int* __restrict__ off_src, bf16* __restrict__ hbuf, int N)
{
    __shared__ float red[8 * 256];
    __shared__ float mslot[8][4];
    __shared__ float dslot[8][4];
    const int t = threadIdx.x;
    const int e8 = t >> 5, g = t & 31;

    if (blockIdx.x >= N) {
        // ---------------- GIN aggregate (slot-vectorized b128 gathers) -----
        const int i = blockIdx.x - N;
        const int beg = off_src[i], end = off_src[i + 1];
        float a0 = 0, a1 = 0, a2 = 0, a3 = 0, a4 = 0, a5 = 0, a6 = 0, a7 = 0;
        if (e8 == 0) {
            bf16x8 xv = *(const bf16x8*)&xb[(size_t)i * DINC + g * 8];
            a0 = (float)xv[0]; a1 = (float)xv[1]; a2 = (float)xv[2]; a3 = (float)xv[3];
            a4 = (float)xv[4]; a5 = (float)xv[5]; a6 = (float)xv[6]; a7 = (float)xv[7];
        }
        for (int j = beg + e8; j < end; j += 8) {
            const int s = csr_gin[j];
            bf16x8 v = *(const bf16x8*)&xb[(size_t)s * DINC + g * 8];
            a0 += (float)v[0]; a1 += (float)v[1]; a2 += (float)v[2]; a3 += (float)v[3];
            a4 += (float)v[4]; a5 += (float)v[5]; a6 += (float)v[6]; a7 += (float)v[7];
        }
        f32x4 lo = {a0, a1, a2, a3}, hi = {a4, a5, a6, a7};
        *(f32x4*)&red[e8 * 256 + g * 8]     = lo;
        *(f32x4*)&red[e8 * 256 + g * 8 + 4] = hi;
        __syncthreads();
        float acc = 0.0f;
#pragma unroll
        for (int s = 0; s < 8; ++s) acc += red[s * 256 + t];
        hbuf[(size_t)i * DINC + t] = (bf16)acc;
        return;
    }

    // ---------------- GATv2, single-pass online softmax ----------------
    const int d = blockIdx.x;
    const int beg = off_dst[d];
    const int deg = off_dst[d + 1] - beg;
    const int cnt = deg + 1;

    float xr8[8], at8[8];
    {
        bf16x8 xv = *(const bf16x8*)&xlr[(size_t)d * HIDC + 256 + g * 8];
#pragma unroll
        for (int f = 0; f < 8; ++f) xr8[f] = (float)xv[f];
        float4 q0 = *(const float4*)&att[g * 8];
        float4 q1 = *(const float4*)&att[g * 8 + 4];
        at8[0] = q0.x; at8[1] = q0.y; at8[2] = q0.z; at8[3] = q0.w;
        at8[4] = q1.x; at8[5] = q1.y; at8[6] = q1.z; at8[7] = q1.w;
    }

    float m = -1e30f, den = 0.0f;
    float a[8];
#pragma unroll
    for (int f = 0; f < 8; ++f) a[f] = 0.0f;

    for (int jj = e8; jj < cnt; jj += 8) {
        const int s = (jj < deg) ? csr_src[beg + jj] : d;
        bf16x8 v = *(const bf16x8*)&xlr[(size_t)s * HIDC + g * 8];
        float vf[8];
        float p = 0.0f;
#pragma unroll
        for (int f = 0; f < 8; ++f) {
            vf[f] = (float)v[f];
            p += lrelu02(vf[f] + xr8[f]) * at8[f];
        }
        p += __shfl_xor(p, 1);
        p += __shfl_xor(p, 2);
        p += __shfl_xor(p, 4);          // p uniform within 8-lane head-group
        const float nm = fmaxf(m, p);
        const float r = __expf(m - nm); // 1 when m unchanged
        const float w = __expf(p - nm);
        den = den * r + w;
#pragma unroll
        for (int f = 0; f < 8; ++f) a[f] = fmaf(a[f], r, w * vf[f]);
        m = nm;
    }

    {
        f32x4 lo = {a[0], a[1], a[2], a[3]}, hi = {a[4], a[5], a[6], a[7]};
        *(f32x4*)&red[e8 * 256 + g * 8]     = lo;
        *(f32x4*)&red[e8 * 256 + g * 8 + 4] = hi;
        if ((g & 7) == 0) { mslot[e8][g >> 3] = m; dslot[e8][g >> 3] = den; }
    }
    __syncthreads();

    const int h = t >> 6;
    float M = mslot[0][h];
#pragma unroll
    for (int s2 = 1; s2 < 8; ++s2) M = fmaxf(M, mslot[s2][h]);
    float accv = 0.0f, dd = 0.0f;
#pragma unroll
    for (int s2 = 0; s2 < 8; ++s2) {
        const float sc = __expf(mslot[s2][h] - M);   // 0 for empty slots
        accv = fmaf(sc, red[s2 * 256 + t], accv);
        dd   = fmaf(sc, dslot[s2][h], dd);
    }
    cat[(size_t)d * HIDC + t] = (bf16)(accv / dd + b_gat[t]);
}

// LayerNorm over 512 features (bf16 in, fp32 out)
__global__ __launch_bounds__(256) void layernorm512(
    const bf16* __restrict__ cbuf, const float* __restrict__ g,
    const float* __restrict__ b, float* __restrict__ out)
{
    const int r = blockIdx.x;
    const int t = threadIdx.x;
    typedef __attribute__((ext_vector_type(2))) __bf16 bf16x2;
    bf16x2 pv = *(const bf16x2*)&cbuf[(size_t)r * HIDC + t * 2];
    float v0 = (float)pv[0], v1 = (float)pv[1];
    float s = v0 + v1;
    float q = v0 * v0 + v1 * v1;
    for (int o = 1; o < 64; o <<= 1) {
        s += __shfl_xor(s, o);
        q += __shfl_xor(q, o);
    }
    __shared__ float ls[4], lq[4];
    int w = t >> 6;
    if ((t & 63) == 0) { ls[w] = s; lq[w] = q; }
    __syncthreads();
    s = ls[0] + ls[1] + ls[2] + ls[3];
    q = lq[0] + lq[1] + lq[2] + lq[3];
    float mu  = s * (1.0f / 512.0f);
    float var = q * (1.0f / 512.0f) - mu * mu;
    float rs  = rsqrtf(var + 1e-5f);
    int c0 = t * 2;
    out[(size_t)r * HIDC + c0]     = (v0 - mu) * rs * g[c0]     + b[c0];
    out[(size_t)r * HIDC + c0 + 1] = (v1 - mu) * rs * g[c0 + 1] + b[c0 + 1];
}

// ---------------------------------------------------------------------------
extern "C" void kernel_launch(void* const* d_in, const int* in_sizes, int n_in,
                              void* d_out, int out_size, void* d_ws, size_t ws_size,
                              hipStream_t stream)
{
    const float* x      = (const float*)d_in[0];
    const float* W_l    = (const float*)d_in[1];
    const float* W_r    = (const float*)d_in[2];
    const float* att    = (const float*)d_in[3];
    const float* b_gat  = (const float*)d_in[4];
    const float* gin_W1 = (const float*)d_in[5];
    const float* gin_b1 = (const float*)d_in[6];
    const float* gin_W2 = (const float*)d_in[7];
    const float* gin_b2 = (const float*)d_in[8];
    const float* fus_W  = (const float*)d_in[9];
    const float* fus_b  = (const float*)d_in[10];
    const float* ln_g   = (const float*)d_in[11];
    const float* ln_b   = (const float*)d_in[12];
    const int*   eidx   = (const int*)d_in[13];

    const int E = in_sizes[13] / 2;
    const int N = in_sizes[0] / DINC;  // 8192
    const int* src = eidx;
    const int* dst = eidx + E;

    char* ws = (char*)d_ws;
    size_t off = 0;
    auto alloc = [&](size_t bytes) -> void* {
        void* p = ws + off;
        off = (off + bytes + 255) & ~(size_t)255;
        return p;
    };
    bf16* xb       = (bf16*)alloc((size_t)N * DINC * 2);
    bf16* xlr      = (bf16*)alloc((size_t)N * HIDC * 2);
    bf16* Wlr_t    = (bf16*)alloc((size_t)512 * 256 * 2);
    bf16* W1t      = (bf16*)alloc((size_t)256 * 256 * 2);
    bf16* Wfused_t = (bf16*)alloc((size_t)512 * 512 * 2);
    bf16* Wfbot_t  = (bf16*)alloc((size_t)512 * 256 * 2);
    bf16* W2b      = (bf16*)alloc((size_t)256 * 256 * 2);
    bf16* hbuf     = (bf16*)alloc((size_t)N * DINC * 2);
    bf16* cat      = (bf16*)alloc((size_t)N * HIDC * 2);
    bf16* cbuf     = (bf16*)alloc((size_t)N * HIDC * 2);
    float* bias_comb = (float*)alloc(512 * 4);
    int* cnt_dst = (int*)alloc((size_t)N * 4);   // cnt_dst+cnt_src contiguous
    int* cnt_src = (int*)alloc((size_t)N * 4);
    int* off_dst = (int*)alloc((size_t)(N + 1) * 4);
    int* cur_dst = (int*)alloc((size_t)N * 4);
    int* off_src = (int*)alloc((size_t)(N + 1) * 4);
    int* cur_src = (int*)alloc((size_t)N * 4);
    int* csr_src = (int*)alloc((size_t)E * 4);
    int* csr_gin = (int*)alloc((size_t)E * 4);
    unsigned char* flags  = (unsigned char*)alloc((size_t)E);
    unsigned int*  bitmap = (unsigned int*)alloc((size_t)N * (size_t)N / 8);

    mega_prep<<<dim3(16, 16, 8), 256, 0, stream>>>(
        W_l, W_r, gin_W1, fus_W, gin_b2, fus_b, x, gin_W2,
        Wlr_t, W1t, Wfused_t, Wfbot_t, W2b, xb, bias_comb,
        (u32x4*)cnt_dst, (2 * N) / 4,
        (u32x4*)bitmap, (int)((size_t)N * N / 32 / 4));

    build_hist<<<(E + 255) / 256, 256, 0, stream>>>(src, dst, E, N, cnt_dst, cnt_src, bitmap, flags);
    scan_both<<<2, 1024, 0, stream>>>(cnt_dst, off_dst, cur_dst, cnt_src, off_src, cur_src);

    const int nsc = (E + 255) / 256;
    scatter_gemms<<<nsc + 1024 + 32, 256, 0, stream>>>(
        src, dst, E, cur_dst, cur_src, flags, csr_src, csr_gin,
        xb, Wlr_t, xlr, Wfbot_t, W2b, Wfused_t);

    gatgin<<<2 * N, 256, 0, stream>>>(xlr, csr_src, off_dst, att, b_gat, cat,
                                      xb, csr_gin, off_src, hbuf, N);

    gemm64<1, 1><<<dim3(4, 128), 256, 0, stream>>>(hbuf, W1t, gin_b1, cat, 256, HIDC, 256);
    gemm64<1, 1><<<dim3(8, 128), 256, 0, stream>>>(cat, Wfused_t, bias_comb, cbuf, 512, HIDC, 0);
    layernorm512<<<N, 256, 0, stream>>>(cbuf, ln_g, ln_b, (float*)d_out);

    (void)n_in; (void)out_size; (void)ws_size;
}